// Round 9
// baseline (181.515 us; speedup 1.0000x reference)
//
#include <hip/hip_runtime.h>

#define N_NODES 50000
#define D_IN    128
#define D_H     256
#define MT      64
#define NGB     782                      // ceil(50000/64) gemm blocks
#define NPART   (NGB * 4)                // per-wave partials

#define NBKT    391                      // ceil(50000/128) dst-buckets of 128 nodes
#define BKT_CAP 3072                     // mean 2046 + 23 sigma for uniform edges
#define EPB     8192                     // edges per bucket_kernel block

typedef short s16x8 __attribute__((ext_vector_type(8)));
typedef short s16x4 __attribute__((ext_vector_type(4)));
typedef float f32x4 __attribute__((ext_vector_type(4)));

__device__ inline ushort f2bf(float f) {           // RNE fp32->bf16
    uint u = __float_as_uint(f);
    return (ushort)((u + 0x7FFFu + ((u >> 16) & 1u)) >> 16);
}
__device__ inline float bf2f(ushort u) { return __uint_as_float(((uint)u) << 16); }

// ================================================================ fused prep: cvt_x | pack_w | zero bucket_fill
// blocks [0,3125): x->bf16 ; [3125,3173): W pack ; 3173: zero fill counters
__global__ __launch_bounds__(256) void prep_kernel(const float* __restrict__ x,
                                                   const float* __restrict__ W1,
                                                   const float* __restrict__ W2,
                                                   ushort* __restrict__ xB,
                                                   ushort* __restrict__ Wp1,
                                                   ushort* __restrict__ Wp2,
                                                   int* __restrict__ bucket_fill) {
    int bid = blockIdx.x, tid = threadIdx.x;
    if (bid < 3125) {
        int i = bid * 256 + tid;                    // < 800000
        float4 a = ((const float4*)x)[(size_t)i * 2];
        float4 b = ((const float4*)x)[(size_t)i * 2 + 1];
        s16x8 o;
        o[0] = (short)f2bf(a.x); o[1] = (short)f2bf(a.y);
        o[2] = (short)f2bf(a.z); o[3] = (short)f2bf(a.w);
        o[4] = (short)f2bf(b.x); o[5] = (short)f2bf(b.y);
        o[6] = (short)f2bf(b.z); o[7] = (short)f2bf(b.w);
        ((s16x8*)xB)[i] = o;
    } else if (bid < 3173) {
        int t = (bid - 3125) * 256 + tid;
        const float* W; ushort* Wp; int u;
        if (t < 4096) { W = W1; Wp = Wp1; u = t; }
        else          { W = W2; Wp = Wp2; u = t - 4096; }
        int l = u & 63, gs = u >> 6;
        int g = gs & 15, s = gs >> 4;
        int col = g * 16 + (l & 15), q = l >> 4;
        s16x8 o;
#pragma unroll
        for (int j = 0; j < 8; j++) {
            int k = s * 32 + q * 8 + j;
            o[j] = (short)f2bf(W[(size_t)k * D_H + col]);
        }
        *(s16x8*)(Wp + (size_t)u * 8) = o;
    } else {
        for (int i = tid; i < NBKT; i += 256) bucket_fill[i] = 0;
    }
}

// ================================================================ pass A: bucket edges by dst>>7
__global__ __launch_bounds__(256) void bucket_kernel(const int* __restrict__ ei,
                                                     int* __restrict__ bucket_fill,
                                                     uint* __restrict__ bucket_buf, int E) {
    __shared__ int cnt[NBKT], gbase[NBKT], fill2[NBKT];
    int tid = threadIdx.x;
    int e0 = blockIdx.x * EPB;
    for (int i = tid; i < NBKT; i += 256) { cnt[i] = 0; fill2[i] = 0; }
    __syncthreads();
    int dstv[32];
#pragma unroll
    for (int j = 0; j < 32; j++) {
        int e = e0 + j * 256 + tid;
        dstv[j] = (e < E) ? ei[E + e] : -1;
        if (dstv[j] >= 0) atomicAdd(&cnt[dstv[j] >> 7], 1);
    }
    __syncthreads();
    for (int i = tid; i < NBKT; i += 256) {
        int c = cnt[i];
        gbase[i] = c ? atomicAdd(&bucket_fill[i], c) : 0;
    }
    __syncthreads();
#pragma unroll
    for (int j = 0; j < 32; j++) {
        int e = e0 + j * 256 + tid;
        if (dstv[j] >= 0) {
            int src = ei[e];
            int b = dstv[j] >> 7;
            int p = atomicAdd(&fill2[b], 1);
            bucket_buf[(size_t)b * BKT_CAP + gbase[b] + p] =
                ((uint)(dstv[j] & 127) << 16) | (uint)src;
        }
    }
}

// ================================================================ pass B: per-bucket LDS counting sort + gather
__global__ __launch_bounds__(512) void gather_bucket_kernel(const ushort* __restrict__ xB,
                                                            const float* __restrict__ eps,
                                                            const int* __restrict__ bucket_fill,
                                                            const uint* __restrict__ bucket_buf,
                                                            ushort* __restrict__ h) {
    __shared__ uint   raw[BKT_CAP];
    __shared__ ushort srt[BKT_CAP];
    __shared__ int cnt[128], off[128], f2[128];
    int b = blockIdx.x, tid = threadIdx.x;
    int n = bucket_fill[b];
    if (n > BKT_CAP) n = BKT_CAP;
    for (int i = tid; i < n; i += 512) raw[i] = bucket_buf[(size_t)b * BKT_CAP + i];
    if (tid < 128) { cnt[tid] = 0; f2[tid] = 0; }
    __syncthreads();
    for (int i = tid; i < n; i += 512) atomicAdd(&cnt[raw[i] >> 16], 1);
    __syncthreads();
    if (tid < 128) off[tid] = cnt[tid];
    __syncthreads();
    for (int s2 = 1; s2 < 128; s2 <<= 1) {
        int t = (tid < 128 && tid >= s2) ? off[tid - s2] : 0;
        __syncthreads();
        if (tid < 128) off[tid] += t;
        __syncthreads();
    }
    for (int i = tid; i < n; i += 512) {
        uint r = raw[i];
        int d = r >> 16;
        int p = atomicAdd(&f2[d], 1);
        srt[(off[d] - cnt[d]) + p] = (ushort)(r & 0xFFFFu);
    }
    __syncthreads();

    int grp = tid >> 5, lane = tid & 31;
    int c = lane << 2;
    float s = 1.0f + eps[0];
    for (int dl = grp; dl < 128; dl += 16) {
        int d = b * 128 + dl;
        if (d >= N_NODES) break;
        int st = off[dl] - cnt[dl], cn = cnt[dl];
        s16x4 sv = *(const s16x4*)(xB + (size_t)d * D_IN + c);
        float a0 = bf2f((ushort)sv[0]) * s, a1 = bf2f((ushort)sv[1]) * s,
              a2 = bf2f((ushort)sv[2]) * s, a3 = bf2f((ushort)sv[3]) * s;
        int j = 0;
        for (; j + 3 < cn; j += 4) {
            int s0 = srt[st + j],     s1 = srt[st + j + 1];
            int s2 = srt[st + j + 2], s3 = srt[st + j + 3];
            s16x4 v0 = *(const s16x4*)(xB + (size_t)s0 * D_IN + c);
            s16x4 v1 = *(const s16x4*)(xB + (size_t)s1 * D_IN + c);
            s16x4 v2 = *(const s16x4*)(xB + (size_t)s2 * D_IN + c);
            s16x4 v3 = *(const s16x4*)(xB + (size_t)s3 * D_IN + c);
            a0 += bf2f((ushort)v0[0]) + bf2f((ushort)v1[0]) + bf2f((ushort)v2[0]) + bf2f((ushort)v3[0]);
            a1 += bf2f((ushort)v0[1]) + bf2f((ushort)v1[1]) + bf2f((ushort)v2[1]) + bf2f((ushort)v3[1]);
            a2 += bf2f((ushort)v0[2]) + bf2f((ushort)v1[2]) + bf2f((ushort)v2[2]) + bf2f((ushort)v3[2]);
            a3 += bf2f((ushort)v0[3]) + bf2f((ushort)v1[3]) + bf2f((ushort)v2[3]) + bf2f((ushort)v3[3]);
        }
        for (; j < cn; j++) {
            int s0 = srt[st + j];
            s16x4 v0 = *(const s16x4*)(xB + (size_t)s0 * D_IN + c);
            a0 += bf2f((ushort)v0[0]); a1 += bf2f((ushort)v0[1]);
            a2 += bf2f((ushort)v0[2]); a3 += bf2f((ushort)v0[3]);
        }
        s16x4 o;
        o[0] = (short)f2bf(a0); o[1] = (short)f2bf(a1);
        o[2] = (short)f2bf(a2); o[3] = (short)f2bf(a3);
        *(s16x4*)(h + (size_t)d * D_IN + c) = o;
    }
}

// ================================================================ GEMM1 (MFMA, MT=64): h1B = h @ W1 + per-wave BN1 partials
__global__ __launch_bounds__(256) void gemm1_kernel(const ushort* __restrict__ hB,
                                                    const ushort* __restrict__ Wp,
                                                    ushort* __restrict__ h1B,
                                                    float* __restrict__ partial) {
    __shared__ ushort A[MT * D_IN];   // 64x128 bf16 = 16 KB, row stride 256 B, XOR-swizzled
    int tid = threadIdx.x, lane = tid & 63, w = tid >> 6;
    int row0 = blockIdx.x * MT;
    for (int i = tid; i < 1024; i += 256) {
        int r = i >> 4, cb = (i & 15) << 4;
        int row = row0 + r;
        s16x8 v = {};
        if (row < N_NODES) v = *(const s16x8*)(hB + (size_t)row * D_IN + (cb >> 1));
        *(s16x8*)((char*)A + r * 256 + (cb ^ ((r & 7) << 4))) = v;
    }
    __syncthreads();
    int m = lane & 15, q = lane >> 4;
    int rloc = w * 16 + m;            // (rloc & 7) == (m & 7)
    int sw = (m & 7) << 4;
    f32x4 acc[16] = {};
    const s16x8* B = (const s16x8*)Wp;
#pragma unroll
    for (int s = 0; s < 4; s++) {
        s16x8 a = *(const s16x8*)((char*)A + rloc * 256 + ((s * 64 + q * 16) ^ sw));
#pragma unroll
        for (int f = 0; f < 16; f++) {
            acc[f] = __builtin_amdgcn_mfma_f32_16x16x32_bf16(a, B[(s * 16 + f) * 64 + lane], acc[f], 0, 0, 0);
        }
    }
#pragma unroll
    for (int f = 0; f < 16; f++) {
        int col = f * 16 + m;
        float s1 = 0.f, s2 = 0.f;
#pragma unroll
        for (int j = 0; j < 4; j++) {
            float v = acc[f][j];
            int row = row0 + w * 16 + q * 4 + j;
            if (row < N_NODES) h1B[(size_t)row * D_H + col] = f2bf(v);
            s1 += v; s2 = fmaf(v, v, s2);
        }
        s1 += __shfl_xor(s1, 16, 64); s1 += __shfl_xor(s1, 32, 64);
        s2 += __shfl_xor(s2, 16, 64); s2 += __shfl_xor(s2, 32, 64);
        if (lane < 16) {
            partial[((size_t)blockIdx.x * 4 + w) * 512 + col] = s1;
            partial[((size_t)blockIdx.x * 4 + w) * 512 + 256 + col] = s2;
        }
    }
}

// ================================================================ BN finalize (over NPART wave-partials)
__global__ __launch_bounds__(256) void bn_finalize_kernel(const float* __restrict__ partial,
                                                          const float* __restrict__ gamma,
                                                          const float* __restrict__ beta,
                                                          float* __restrict__ scale,
                                                          float* __restrict__ shift) {
    int s = blockIdx.x;
    int tid = threadIdx.x;
    float sum = 0.f, sq = 0.f;
    for (int b = tid; b < NPART; b += 256) {
        sum += partial[(size_t)b * 512 + s];
        sq  += partial[(size_t)b * 512 + 256 + s];
    }
    __shared__ float rs[256], rq[256];
    rs[tid] = sum; rq[tid] = sq;
    __syncthreads();
    for (int off = 128; off > 0; off >>= 1) {
        if (tid < off) { rs[tid] += rs[tid + off]; rq[tid] += rq[tid + off]; }
        __syncthreads();
    }
    if (tid == 0) {
        float inv  = 1.0f / (float)N_NODES;
        float mean = rs[0] * inv;
        float var  = rq[0] * inv - mean * mean;
        float sc   = gamma[s] * rsqrtf(var + 1e-5f);
        scale[s] = sc;
        shift[s] = fmaf(-mean, sc, beta[s]);
    }
}

// ================================================================ GEMM2 (MFMA, MT=64): h2B = relu(BN1(h1B)) @ W2 + BN2 partials
__global__ __launch_bounds__(256) void gemm2_kernel(const ushort* __restrict__ h1B,
                                                    const ushort* __restrict__ Wp,
                                                    const float* __restrict__ scale1,
                                                    const float* __restrict__ shift1,
                                                    ushort* __restrict__ h2B,
                                                    float* __restrict__ partial) {
    __shared__ ushort A[MT * D_H];    // 64x256 bf16 = 32 KB, row stride 512 B, swizzled
    int tid = threadIdx.x, lane = tid & 63, w = tid >> 6;
    int row0 = blockIdx.x * MT;
    for (int i = tid; i < 2048; i += 256) {
        int r = i >> 5, cb = (i & 31) << 4;
        int row = row0 + r, c0 = cb >> 1;
        s16x8 o = {};
        if (row < N_NODES) {
            s16x8 in = *(const s16x8*)(h1B + (size_t)row * D_H + c0);
            float4 sc0 = *(const float4*)(scale1 + c0), sc1 = *(const float4*)(scale1 + c0 + 4);
            float4 sh0 = *(const float4*)(shift1 + c0), sh1 = *(const float4*)(shift1 + c0 + 4);
            o[0] = (short)f2bf(fmaxf(fmaf(bf2f((ushort)in[0]), sc0.x, sh0.x), 0.f));
            o[1] = (short)f2bf(fmaxf(fmaf(bf2f((ushort)in[1]), sc0.y, sh0.y), 0.f));
            o[2] = (short)f2bf(fmaxf(fmaf(bf2f((ushort)in[2]), sc0.z, sh0.z), 0.f));
            o[3] = (short)f2bf(fmaxf(fmaf(bf2f((ushort)in[3]), sc0.w, sh0.w), 0.f));
            o[4] = (short)f2bf(fmaxf(fmaf(bf2f((ushort)in[4]), sc1.x, sh1.x), 0.f));
            o[5] = (short)f2bf(fmaxf(fmaf(bf2f((ushort)in[5]), sc1.y, sh1.y), 0.f));
            o[6] = (short)f2bf(fmaxf(fmaf(bf2f((ushort)in[6]), sc1.z, sh1.z), 0.f));
            o[7] = (short)f2bf(fmaxf(fmaf(bf2f((ushort)in[7]), sc1.w, sh1.w), 0.f));
        }
        *(s16x8*)((char*)A + r * 512 + (cb ^ ((r & 7) << 4))) = o;
    }
    __syncthreads();
    int m = lane & 15, q = lane >> 4;
    int rloc = w * 16 + m;
    int sw = (m & 7) << 4;
    f32x4 acc[16] = {};
    const s16x8* B = (const s16x8*)Wp;
#pragma unroll
    for (int s = 0; s < 8; s++) {
        s16x8 a = *(const s16x8*)((char*)A + rloc * 512 + ((s * 64 + q * 16) ^ sw));
#pragma unroll
        for (int f = 0; f < 16; f++) {
            acc[f] = __builtin_amdgcn_mfma_f32_16x16x32_bf16(a, B[(s * 16 + f) * 64 + lane], acc[f], 0, 0, 0);
        }
    }
#pragma unroll
    for (int f = 0; f < 16; f++) {
        int col = f * 16 + m;
        float s1 = 0.f, s2 = 0.f;
#pragma unroll
        for (int j = 0; j < 4; j++) {
            float v = acc[f][j];
            int row = row0 + w * 16 + q * 4 + j;
            if (row < N_NODES) h2B[(size_t)row * D_H + col] = f2bf(v);
            s1 += v; s2 = fmaf(v, v, s2);
        }
        s1 += __shfl_xor(s1, 16, 64); s1 += __shfl_xor(s1, 32, 64);
        s2 += __shfl_xor(s2, 16, 64); s2 += __shfl_xor(s2, 32, 64);
        if (lane < 16) {
            partial[((size_t)blockIdx.x * 4 + w) * 512 + col] = s1;
            partial[((size_t)blockIdx.x * 4 + w) * 512 + 256 + col] = s2;
        }
    }
}

// ================================================================ final: out = relu(BN2(h2B)) -> fp32
__global__ __launch_bounds__(256) void bn2_apply_kernel(const ushort* __restrict__ h2B,
                                                        const float* __restrict__ scale,
                                                        const float* __restrict__ shift,
                                                        float* __restrict__ out, int total8) {
    int i = blockIdx.x * 256 + threadIdx.x;
    if (i >= total8) return;
    s16x8 v = ((const s16x8*)h2B)[i];
    int c = (i & 31) << 3;
    float4 sc0 = *(const float4*)(scale + c), sc1 = *(const float4*)(scale + c + 4);
    float4 sh0 = *(const float4*)(shift + c), sh1 = *(const float4*)(shift + c + 4);
    float4 o0, o1;
    o0.x = fmaxf(fmaf(bf2f((ushort)v[0]), sc0.x, sh0.x), 0.f);
    o0.y = fmaxf(fmaf(bf2f((ushort)v[1]), sc0.y, sh0.y), 0.f);
    o0.z = fmaxf(fmaf(bf2f((ushort)v[2]), sc0.z, sh0.z), 0.f);
    o0.w = fmaxf(fmaf(bf2f((ushort)v[3]), sc0.w, sh0.w), 0.f);
    o1.x = fmaxf(fmaf(bf2f((ushort)v[4]), sc1.x, sh1.x), 0.f);
    o1.y = fmaxf(fmaf(bf2f((ushort)v[5]), sc1.y, sh1.y), 0.f);
    o1.z = fmaxf(fmaf(bf2f((ushort)v[6]), sc1.z, sh1.z), 0.f);
    o1.w = fmaxf(fmaf(bf2f((ushort)v[7]), sc1.w, sh1.w), 0.f);
    ((float4*)out)[(size_t)i * 2]     = o0;
    ((float4*)out)[(size_t)i * 2 + 1] = o1;
}

// ================================================================
extern "C" void kernel_launch(void* const* d_in, const int* in_sizes, int n_in,
                              void* d_out, int out_size, void* d_ws, size_t ws_size,
                              hipStream_t stream) {
    const float* x      = (const float*)d_in[0];
    const int*   ei     = (const int*)d_in[1];
    const float* eps    = (const float*)d_in[3];
    const float* W1     = (const float*)d_in[4];
    const float* gamma1 = (const float*)d_in[5];
    const float* beta1  = (const float*)d_in[6];
    const float* W2     = (const float*)d_in[7];
    const float* gamma2 = (const float*)d_in[8];
    const float* beta2  = (const float*)d_in[9];
    int E = in_sizes[1] / 2;

    char* ws = (char*)d_ws;
    ushort* xB     = (ushort*)(ws);                 // 12,800,000 B (dead after gather)
    float*  partial= (float*)(ws);                  // 6,406,144 B  (overlaps xB; live from gemm1)
    ushort* hB     = (ushort*)(ws + 12800000);      // 12,800,000 B
    ushort* h1B    = (ushort*)(ws + 25600000);      // 25,600,000 B
    ushort* h2B    = (ushort*)(ws + 51200000);      // 25,600,000 B (overlaps bucket scratch)
    float*  stats  = (float*)(ws + 76800000);       // 4,096 B
    ushort* Wp1    = (ushort*)(ws + 76804096);      // 65,536 B
    ushort* Wp2    = (ushort*)(ws + 76869632);      // 131,072 B -> end 77,000,704
    float* scale1 = stats, *shift1 = stats + 256, *scale2 = stats + 512, *shift2 = stats + 768;
    float* out = (float*)d_out;

    int*  bucket_fill = (int*)(ws + 51200000);      // 391*4 -> pad 2048
    uint* bucket_buf  = (uint*)(ws + 51202048);     // 391*3072*4 = 4,804,608 B

    prep_kernel<<<3174, 256, 0, stream>>>(x, W1, W2, xB, Wp1, Wp2, bucket_fill);
    bucket_kernel<<<(E + EPB - 1) / EPB, 256, 0, stream>>>(ei, bucket_fill, bucket_buf, E);
    gather_bucket_kernel<<<NBKT, 512, 0, stream>>>(xB, eps, bucket_fill, bucket_buf, hB);

    gemm1_kernel<<<NGB, 256, 0, stream>>>(hB, Wp1, h1B, partial);
    bn_finalize_kernel<<<D_H, 256, 0, stream>>>(partial, gamma1, beta1, scale1, shift1);
    gemm2_kernel<<<NGB, 256, 0, stream>>>(h1B, Wp2, scale1, shift1, h2B, partial);
    bn_finalize_kernel<<<D_H, 256, 0, stream>>>(partial, gamma2, beta2, scale2, shift2);
    bn2_apply_kernel<<<(1600000 + 255) / 256, 256, 0, stream>>>(h2B, scale2, shift2, out, 1600000);
}

// Round 10
// 152.047 us; speedup vs baseline: 1.1938x; 1.1938x over previous
//
#include <hip/hip_runtime.h>

#define N_NODES 50000
#define D_IN    128
#define D_H     256
#define MT      16
#define NB      (N_NODES / MT)           // 3125 exact, no tail

#define NBKT    391                      // ceil(50000/128) dst-buckets of 128 nodes
#define BKT_CAP 3072                     // mean 2046 + 23 sigma for uniform edges
#define EPB     8192                     // edges per bucket_kernel block

typedef short s16x8 __attribute__((ext_vector_type(8)));
typedef short s16x4 __attribute__((ext_vector_type(4)));
typedef float f32x4 __attribute__((ext_vector_type(4)));

__device__ inline ushort f2bf(float f) {           // RNE fp32->bf16
    uint u = __float_as_uint(f);
    return (ushort)((u + 0x7FFFu + ((u >> 16) & 1u)) >> 16);
}
__device__ inline float bf2f(ushort u) { return __uint_as_float(((uint)u) << 16); }

// ================================================================ fused prep: cvt_x | pack_w | zero bucket_fill
__global__ __launch_bounds__(256) void prep_kernel(const float* __restrict__ x,
                                                   const float* __restrict__ W1,
                                                   const float* __restrict__ W2,
                                                   ushort* __restrict__ xB,
                                                   ushort* __restrict__ Wp1,
                                                   ushort* __restrict__ Wp2,
                                                   int* __restrict__ bucket_fill) {
    int bid = blockIdx.x, tid = threadIdx.x;
    if (bid < 3125) {
        int i = bid * 256 + tid;                    // < 800000
        float4 a = ((const float4*)x)[(size_t)i * 2];
        float4 b = ((const float4*)x)[(size_t)i * 2 + 1];
        s16x8 o;
        o[0] = (short)f2bf(a.x); o[1] = (short)f2bf(a.y);
        o[2] = (short)f2bf(a.z); o[3] = (short)f2bf(a.w);
        o[4] = (short)f2bf(b.x); o[5] = (short)f2bf(b.y);
        o[6] = (short)f2bf(b.z); o[7] = (short)f2bf(b.w);
        ((s16x8*)xB)[i] = o;
    } else if (bid < 3173) {
        int t = (bid - 3125) * 256 + tid;
        const float* W; ushort* Wp; int u;
        if (t < 4096) { W = W1; Wp = Wp1; u = t; }
        else          { W = W2; Wp = Wp2; u = t - 4096; }
        int l = u & 63, gs = u >> 6;
        int g = gs & 15, s = gs >> 4;
        int col = g * 16 + (l & 15), q = l >> 4;
        s16x8 o;
#pragma unroll
        for (int j = 0; j < 8; j++) {
            int k = s * 32 + q * 8 + j;
            o[j] = (short)f2bf(W[(size_t)k * D_H + col]);
        }
        *(s16x8*)(Wp + (size_t)u * 8) = o;
    } else {
        for (int i = tid; i < NBKT; i += 256) bucket_fill[i] = 0;
    }
}

// ================================================================ pass A: bucket edges by dst>>7
__global__ __launch_bounds__(256) void bucket_kernel(const int* __restrict__ ei,
                                                     int* __restrict__ bucket_fill,
                                                     uint* __restrict__ bucket_buf, int E) {
    __shared__ int cnt[NBKT], gbase[NBKT], fill2[NBKT];
    int tid = threadIdx.x;
    int e0 = blockIdx.x * EPB;
    for (int i = tid; i < NBKT; i += 256) { cnt[i] = 0; fill2[i] = 0; }
    __syncthreads();
    int dstv[32];
#pragma unroll
    for (int j = 0; j < 32; j++) {
        int e = e0 + j * 256 + tid;
        dstv[j] = (e < E) ? ei[E + e] : -1;
        if (dstv[j] >= 0) atomicAdd(&cnt[dstv[j] >> 7], 1);
    }
    __syncthreads();
    for (int i = tid; i < NBKT; i += 256) {
        int c = cnt[i];
        gbase[i] = c ? atomicAdd(&bucket_fill[i], c) : 0;
    }
    __syncthreads();
#pragma unroll
    for (int j = 0; j < 32; j++) {
        int e = e0 + j * 256 + tid;
        if (dstv[j] >= 0) {
            int src = ei[e];
            int b = dstv[j] >> 7;
            int p = atomicAdd(&fill2[b], 1);
            bucket_buf[(size_t)b * BKT_CAP + gbase[b] + p] =
                ((uint)(dstv[j] & 127) << 16) | (uint)src;
        }
    }
}

// ================================================================ pass B: per-bucket LDS counting sort + gather
__global__ __launch_bounds__(512) void gather_bucket_kernel(const ushort* __restrict__ xB,
                                                            const float* __restrict__ eps,
                                                            const int* __restrict__ bucket_fill,
                                                            const uint* __restrict__ bucket_buf,
                                                            ushort* __restrict__ h) {
    __shared__ uint   raw[BKT_CAP];
    __shared__ ushort srt[BKT_CAP];
    __shared__ int cnt[128], off[128], f2[128];
    int b = blockIdx.x, tid = threadIdx.x;
    int n = bucket_fill[b];
    if (n > BKT_CAP) n = BKT_CAP;
    for (int i = tid; i < n; i += 512) raw[i] = bucket_buf[(size_t)b * BKT_CAP + i];
    if (tid < 128) { cnt[tid] = 0; f2[tid] = 0; }
    __syncthreads();
    for (int i = tid; i < n; i += 512) atomicAdd(&cnt[raw[i] >> 16], 1);
    __syncthreads();
    if (tid < 128) off[tid] = cnt[tid];
    __syncthreads();
    for (int s2 = 1; s2 < 128; s2 <<= 1) {
        int t = (tid < 128 && tid >= s2) ? off[tid - s2] : 0;
        __syncthreads();
        if (tid < 128) off[tid] += t;
        __syncthreads();
    }
    for (int i = tid; i < n; i += 512) {
        uint r = raw[i];
        int d = r >> 16;
        int p = atomicAdd(&f2[d], 1);
        srt[(off[d] - cnt[d]) + p] = (ushort)(r & 0xFFFFu);
    }
    __syncthreads();

    int grp = tid >> 5, lane = tid & 31;
    int c = lane << 2;
    float s = 1.0f + eps[0];
    for (int dl = grp; dl < 128; dl += 16) {
        int d = b * 128 + dl;
        if (d >= N_NODES) break;
        int st = off[dl] - cnt[dl], cn = cnt[dl];
        s16x4 sv = *(const s16x4*)(xB + (size_t)d * D_IN + c);
        float a0 = bf2f((ushort)sv[0]) * s, a1 = bf2f((ushort)sv[1]) * s,
              a2 = bf2f((ushort)sv[2]) * s, a3 = bf2f((ushort)sv[3]) * s;
        int j = 0;
        for (; j + 3 < cn; j += 4) {
            int s0 = srt[st + j],     s1 = srt[st + j + 1];
            int s2 = srt[st + j + 2], s3 = srt[st + j + 3];
            s16x4 v0 = *(const s16x4*)(xB + (size_t)s0 * D_IN + c);
            s16x4 v1 = *(const s16x4*)(xB + (size_t)s1 * D_IN + c);
            s16x4 v2 = *(const s16x4*)(xB + (size_t)s2 * D_IN + c);
            s16x4 v3 = *(const s16x4*)(xB + (size_t)s3 * D_IN + c);
            a0 += bf2f((ushort)v0[0]) + bf2f((ushort)v1[0]) + bf2f((ushort)v2[0]) + bf2f((ushort)v3[0]);
            a1 += bf2f((ushort)v0[1]) + bf2f((ushort)v1[1]) + bf2f((ushort)v2[1]) + bf2f((ushort)v3[1]);
            a2 += bf2f((ushort)v0[2]) + bf2f((ushort)v1[2]) + bf2f((ushort)v2[2]) + bf2f((ushort)v3[2]);
            a3 += bf2f((ushort)v0[3]) + bf2f((ushort)v1[3]) + bf2f((ushort)v2[3]) + bf2f((ushort)v3[3]);
        }
        for (; j < cn; j++) {
            int s0 = srt[st + j];
            s16x4 v0 = *(const s16x4*)(xB + (size_t)s0 * D_IN + c);
            a0 += bf2f((ushort)v0[0]); a1 += bf2f((ushort)v0[1]);
            a2 += bf2f((ushort)v0[2]); a3 += bf2f((ushort)v0[3]);
        }
        s16x4 o;
        o[0] = (short)f2bf(a0); o[1] = (short)f2bf(a1);
        o[2] = (short)f2bf(a2); o[3] = (short)f2bf(a3);
        *(s16x4*)(h + (size_t)d * D_IN + c) = o;
    }
}

// ================================================================ GEMM1 (MFMA, MT=16): h1B = h @ W1 + BN1 stats
__global__ __launch_bounds__(256) void gemm1_kernel(const ushort* __restrict__ hB,
                                                    const ushort* __restrict__ Wp,
                                                    ushort* __restrict__ h1B,
                                                    float* __restrict__ partial) {
    __shared__ ushort A[MT * D_IN];   // 16x128 bf16, XOR-swizzled rows (stride 256 B)
    int tid = threadIdx.x, lane = tid & 63, w = tid >> 6;
    int row0 = blockIdx.x * MT;
    {
        int r = tid >> 4, cb = (tid & 15) << 4;
        s16x8 v = *(const s16x8*)(hB + (size_t)(row0 + r) * D_IN + (cb >> 1));
        *(s16x8*)((char*)A + r * 256 + (cb ^ ((r & 7) << 4))) = v;
    }
    __syncthreads();
    int m = lane & 15, q = lane >> 4;
    int sw = (m & 7) << 4;
    f32x4 acc[4] = {};
    const s16x8* B = (const s16x8*)Wp;
#pragma unroll
    for (int s = 0; s < 4; s++) {
        s16x8 a = *(const s16x8*)((char*)A + m * 256 + ((s * 64 + q * 16) ^ sw));
#pragma unroll
        for (int f = 0; f < 4; f++) {
            int g = w * 4 + f;
            s16x8 b = B[(s * 16 + g) * 64 + lane];
            acc[f] = __builtin_amdgcn_mfma_f32_16x16x32_bf16(a, b, acc[f], 0, 0, 0);
        }
    }
#pragma unroll
    for (int f = 0; f < 4; f++) {
        int g = w * 4 + f, col = g * 16 + m;
        float s1 = 0.f, s2 = 0.f;
#pragma unroll
        for (int j = 0; j < 4; j++) {
            float v = acc[f][j];
            h1B[(size_t)(row0 + q * 4 + j) * D_H + col] = f2bf(v);
            s1 += v; s2 = fmaf(v, v, s2);
        }
        s1 += __shfl_xor(s1, 16, 64); s1 += __shfl_xor(s1, 32, 64);
        s2 += __shfl_xor(s2, 16, 64); s2 += __shfl_xor(s2, 32, 64);
        if (lane < 16) {
            partial[(size_t)blockIdx.x * 512 + col] = s1;
            partial[(size_t)blockIdx.x * 512 + 256 + col] = s2;
        }
    }
}

// ================================================================ BN finalize
__global__ __launch_bounds__(256) void bn_finalize_kernel(const float* __restrict__ partial,
                                                          const float* __restrict__ gamma,
                                                          const float* __restrict__ beta,
                                                          float* __restrict__ scale,
                                                          float* __restrict__ shift) {
    int s = blockIdx.x;
    int tid = threadIdx.x;
    float sum = 0.f, sq = 0.f;
    for (int b = tid; b < NB; b += 256) {
        sum += partial[(size_t)b * 512 + s];
        sq  += partial[(size_t)b * 512 + 256 + s];
    }
    __shared__ float rs[256], rq[256];
    rs[tid] = sum; rq[tid] = sq;
    __syncthreads();
    for (int off = 128; off > 0; off >>= 1) {
        if (tid < off) { rs[tid] += rs[tid + off]; rq[tid] += rq[tid + off]; }
        __syncthreads();
    }
    if (tid == 0) {
        float inv  = 1.0f / (float)N_NODES;
        float mean = rs[0] * inv;
        float var  = rq[0] * inv - mean * mean;
        float sc   = gamma[s] * rsqrtf(var + 1e-5f);
        scale[s] = sc;
        shift[s] = fmaf(-mean, sc, beta[s]);
    }
}

// ================================================================ GEMM2 (MFMA, MT=16): h2B = relu(BN1(h1B)) @ W2 + BN2 stats
__global__ __launch_bounds__(256) void gemm2_kernel(const ushort* __restrict__ h1B,
                                                    const ushort* __restrict__ Wp,
                                                    const float* __restrict__ scale1,
                                                    const float* __restrict__ shift1,
                                                    ushort* __restrict__ h2B,
                                                    float* __restrict__ partial) {
    __shared__ ushort A[MT * D_H];    // 16x256 bf16, swizzled (stride 512 B)
    int tid = threadIdx.x, lane = tid & 63, w = tid >> 6;
    int row0 = blockIdx.x * MT;
    {
        int r = tid >> 4, c0 = (tid & 15) << 4;
        const ushort* srcp = h1B + (size_t)(row0 + r) * D_H + c0;
        s16x8 in0 = *(const s16x8*)(srcp);
        s16x8 in1 = *(const s16x8*)(srcp + 8);
        s16x8 lo, hi;
#pragma unroll
        for (int i = 0; i < 8; i++) {
            float v = fmaxf(fmaf(bf2f((ushort)in0[i]), scale1[c0 + i], shift1[c0 + i]), 0.f);
            lo[i] = (short)f2bf(v);
        }
#pragma unroll
        for (int i = 0; i < 8; i++) {
            float v = fmaxf(fmaf(bf2f((ushort)in1[i]), scale1[c0 + 8 + i], shift1[c0 + 8 + i]), 0.f);
            hi[i] = (short)f2bf(v);
        }
        int swr = (r & 7) << 4, base = r * 512, cb = c0 * 2;
        *(s16x8*)((char*)A + base + ( cb        ^ swr)) = lo;
        *(s16x8*)((char*)A + base + ((cb + 16)  ^ swr)) = hi;
    }
    __syncthreads();
    int m = lane & 15, q = lane >> 4;
    int sw = (m & 7) << 4;
    f32x4 acc[4] = {};
    const s16x8* B = (const s16x8*)Wp;
#pragma unroll
    for (int s = 0; s < 8; s++) {
        s16x8 a = *(const s16x8*)((char*)A + m * 512 + ((s * 64 + q * 16) ^ sw));
#pragma unroll
        for (int f = 0; f < 4; f++) {
            int g = w * 4 + f;
            s16x8 b = B[(s * 16 + g) * 64 + lane];
            acc[f] = __builtin_amdgcn_mfma_f32_16x16x32_bf16(a, b, acc[f], 0, 0, 0);
        }
    }
#pragma unroll
    for (int f = 0; f < 4; f++) {
        int g = w * 4 + f, col = g * 16 + m;
        float s1 = 0.f, s2 = 0.f;
#pragma unroll
        for (int j = 0; j < 4; j++) {
            float v = acc[f][j];
            h2B[(size_t)(row0 + q * 4 + j) * D_H + col] = f2bf(v);
            s1 += v; s2 = fmaf(v, v, s2);
        }
        s1 += __shfl_xor(s1, 16, 64); s1 += __shfl_xor(s1, 32, 64);
        s2 += __shfl_xor(s2, 16, 64); s2 += __shfl_xor(s2, 32, 64);
        if (lane < 16) {
            partial[(size_t)blockIdx.x * 512 + col] = s1;
            partial[(size_t)blockIdx.x * 512 + 256 + col] = s2;
        }
    }
}

// ================================================================ final: out = relu(BN2(h2B)) -> fp32
__global__ __launch_bounds__(256) void bn2_apply_kernel(const ushort* __restrict__ h2B,
                                                        const float* __restrict__ scale,
                                                        const float* __restrict__ shift,
                                                        float* __restrict__ out, int total8) {
    int i = blockIdx.x * 256 + threadIdx.x;
    if (i >= total8) return;
    s16x8 v = ((const s16x8*)h2B)[i];
    int c = (i & 31) << 3;
    float4 sc0 = *(const float4*)(scale + c), sc1 = *(const float4*)(scale + c + 4);
    float4 sh0 = *(const float4*)(shift + c), sh1 = *(const float4*)(shift + c + 4);
    float4 o0, o1;
    o0.x = fmaxf(fmaf(bf2f((ushort)v[0]), sc0.x, sh0.x), 0.f);
    o0.y = fmaxf(fmaf(bf2f((ushort)v[1]), sc0.y, sh0.y), 0.f);
    o0.z = fmaxf(fmaf(bf2f((ushort)v[2]), sc0.z, sh0.z), 0.f);
    o0.w = fmaxf(fmaf(bf2f((ushort)v[3]), sc0.w, sh0.w), 0.f);
    o1.x = fmaxf(fmaf(bf2f((ushort)v[4]), sc1.x, sh1.x), 0.f);
    o1.y = fmaxf(fmaf(bf2f((ushort)v[5]), sc1.y, sh1.y), 0.f);
    o1.z = fmaxf(fmaf(bf2f((ushort)v[6]), sc1.z, sh1.z), 0.f);
    o1.w = fmaxf(fmaf(bf2f((ushort)v[7]), sc1.w, sh1.w), 0.f);
    ((float4*)out)[(size_t)i * 2]     = o0;
    ((float4*)out)[(size_t)i * 2 + 1] = o1;
}

// ================================================================
extern "C" void kernel_launch(void* const* d_in, const int* in_sizes, int n_in,
                              void* d_out, int out_size, void* d_ws, size_t ws_size,
                              hipStream_t stream) {
    const float* x      = (const float*)d_in[0];
    const int*   ei     = (const int*)d_in[1];
    const float* eps    = (const float*)d_in[3];
    const float* W1     = (const float*)d_in[4];
    const float* gamma1 = (const float*)d_in[5];
    const float* beta1  = (const float*)d_in[6];
    const float* W2     = (const float*)d_in[7];
    const float* gamma2 = (const float*)d_in[8];
    const float* beta2  = (const float*)d_in[9];
    int E = in_sizes[1] / 2;

    char* ws = (char*)d_ws;
    ushort* xB     = (ushort*)(ws);                 // 12,800,000 B (dead after gather)
    float*  partial= (float*)(ws);                  // 6,400,000 B  (overlaps xB; live from gemm1)
    ushort* hB     = (ushort*)(ws + 12800000);      // 12,800,000 B
    ushort* h1B    = (ushort*)(ws + 25600000);      // 25,600,000 B
    ushort* h2B    = (ushort*)(ws + 51200000);      // 25,600,000 B (overlaps bucket scratch)
    float*  stats  = (float*)(ws + 76800000);       // 4,096 B
    ushort* Wp1    = (ushort*)(ws + 76804096);      // 65,536 B
    ushort* Wp2    = (ushort*)(ws + 76869632);      // 131,072 B -> end 77,000,704
    float* scale1 = stats, *shift1 = stats + 256, *scale2 = stats + 512, *shift2 = stats + 768;
    float* out = (float*)d_out;

    int*  bucket_fill = (int*)(ws + 51200000);      // 391*4 -> pad 2048
    uint* bucket_buf  = (uint*)(ws + 51202048);     // 391*3072*4 = 4,804,608 B

    prep_kernel<<<3174, 256, 0, stream>>>(x, W1, W2, xB, Wp1, Wp2, bucket_fill);
    bucket_kernel<<<(E + EPB - 1) / EPB, 256, 0, stream>>>(ei, bucket_fill, bucket_buf, E);
    gather_bucket_kernel<<<NBKT, 512, 0, stream>>>(xB, eps, bucket_fill, bucket_buf, hB);

    gemm1_kernel<<<NB, 256, 0, stream>>>(hB, Wp1, h1B, partial);
    bn_finalize_kernel<<<D_H, 256, 0, stream>>>(partial, gamma1, beta1, scale1, shift1);
    gemm2_kernel<<<NB, 256, 0, stream>>>(h1B, Wp2, scale1, shift1, h2B, partial);
    bn_finalize_kernel<<<D_H, 256, 0, stream>>>(partial, gamma2, beta2, scale2, shift2);
    bn2_apply_kernel<<<(1600000 + 255) / 256, 256, 0, stream>>>(h2B, scale2, shift2, out, 1600000);
}

// Round 12
// 135.245 us; speedup vs baseline: 1.3421x; 1.1242x over previous
//
#include <hip/hip_runtime.h>

#define N_NODES 50000
#define D_IN    128
#define D_H     256
#define MT      32
#define NGB     1563                     // ceil(50000/32), tail block has 16 rows
#define NPART   NGB

#define NBKT    391                      // ceil(50000/128) dst-buckets of 128 nodes
#define BKT_CAP 3072                     // mean 2046 + 23 sigma for uniform edges
#define EPB     8192                     // edges per bucket_kernel block

typedef short s16x8 __attribute__((ext_vector_type(8)));
typedef short s16x4 __attribute__((ext_vector_type(4)));
typedef float f32x4 __attribute__((ext_vector_type(4)));

__device__ inline ushort f2bf(float f) {           // RNE fp32->bf16
    uint u = __float_as_uint(f);
    return (ushort)((u + 0x7FFFu + ((u >> 16) & 1u)) >> 16);
}
__device__ inline float bf2f(ushort u) { return __uint_as_float(((uint)u) << 16); }

// ================================================================ fused prep: cvt_x | pack_w | zero bucket_fill
__global__ __launch_bounds__(256) void prep_kernel(const float* __restrict__ x,
                                                   const float* __restrict__ W1,
                                                   const float* __restrict__ W2,
                                                   ushort* __restrict__ xB,
                                                   ushort* __restrict__ Wp1,
                                                   ushort* __restrict__ Wp2,
                                                   int* __restrict__ bucket_fill) {
    int bid = blockIdx.x, tid = threadIdx.x;
    if (bid < 3125) {
        int i = bid * 256 + tid;                    // < 800000
        float4 a = ((const float4*)x)[(size_t)i * 2];
        float4 b = ((const float4*)x)[(size_t)i * 2 + 1];
        s16x8 o;
        o[0] = (short)f2bf(a.x); o[1] = (short)f2bf(a.y);
        o[2] = (short)f2bf(a.z); o[3] = (short)f2bf(a.w);
        o[4] = (short)f2bf(b.x); o[5] = (short)f2bf(b.y);
        o[6] = (short)f2bf(b.z); o[7] = (short)f2bf(b.w);
        ((s16x8*)xB)[i] = o;
    } else if (bid < 3173) {
        int t = (bid - 3125) * 256 + tid;
        const float* W; ushort* Wp; int u;
        if (t < 4096) { W = W1; Wp = Wp1; u = t; }
        else          { W = W2; Wp = Wp2; u = t - 4096; }
        int l = u & 63, gs = u >> 6;
        int g = gs & 15, s = gs >> 4;
        int col = g * 16 + (l & 15), q = l >> 4;
        s16x8 o;
#pragma unroll
        for (int j = 0; j < 8; j++) {
            int k = s * 32 + q * 8 + j;
            o[j] = (short)f2bf(W[(size_t)k * D_H + col]);
        }
        *(s16x8*)(Wp + (size_t)u * 8) = o;
    } else {
        for (int i = tid; i < NBKT; i += 256) bucket_fill[i] = 0;
    }
}

// ================================================================ pass A: bucket edges by dst>>7
__global__ __launch_bounds__(256) void bucket_kernel(const int* __restrict__ ei,
                                                     int* __restrict__ bucket_fill,
                                                     uint* __restrict__ bucket_buf, int E) {
    __shared__ int cnt[NBKT], gbase[NBKT], fill2[NBKT];
    int tid = threadIdx.x;
    int e0 = blockIdx.x * EPB;
    for (int i = tid; i < NBKT; i += 256) { cnt[i] = 0; fill2[i] = 0; }
    __syncthreads();
    int dstv[32];
#pragma unroll
    for (int j = 0; j < 32; j++) {
        int e = e0 + j * 256 + tid;
        dstv[j] = (e < E) ? ei[E + e] : -1;
        if (dstv[j] >= 0) atomicAdd(&cnt[dstv[j] >> 7], 1);
    }
    __syncthreads();
    for (int i = tid; i < NBKT; i += 256) {
        int c = cnt[i];
        gbase[i] = c ? atomicAdd(&bucket_fill[i], c) : 0;
    }
    __syncthreads();
#pragma unroll
    for (int j = 0; j < 32; j++) {
        int e = e0 + j * 256 + tid;
        if (dstv[j] >= 0) {
            int src = ei[e];
            int b = dstv[j] >> 7;
            int p = atomicAdd(&fill2[b], 1);
            bucket_buf[(size_t)b * BKT_CAP + gbase[b] + p] =
                ((uint)(dstv[j] & 127) << 16) | (uint)src;
        }
    }
}

// ================================================================ pass B: per-bucket LDS counting sort + gather
__global__ __launch_bounds__(512) void gather_bucket_kernel(const ushort* __restrict__ xB,
                                                            const float* __restrict__ eps,
                                                            const int* __restrict__ bucket_fill,
                                                            const uint* __restrict__ bucket_buf,
                                                            ushort* __restrict__ h) {
    __shared__ uint   raw[BKT_CAP];
    __shared__ ushort srt[BKT_CAP];
    __shared__ int cnt[128], off[128], f2[128];
    int b = blockIdx.x, tid = threadIdx.x;
    int n = bucket_fill[b];
    if (n > BKT_CAP) n = BKT_CAP;
    for (int i = tid; i < n; i += 512) raw[i] = bucket_buf[(size_t)b * BKT_CAP + i];
    if (tid < 128) { cnt[tid] = 0; f2[tid] = 0; }
    __syncthreads();
    for (int i = tid; i < n; i += 512) atomicAdd(&cnt[raw[i] >> 16], 1);
    __syncthreads();
    if (tid < 128) off[tid] = cnt[tid];
    __syncthreads();
    for (int s2 = 1; s2 < 128; s2 <<= 1) {
        int t = (tid < 128 && tid >= s2) ? off[tid - s2] : 0;
        __syncthreads();
        if (tid < 128) off[tid] += t;
        __syncthreads();
    }
    for (int i = tid; i < n; i += 512) {
        uint r = raw[i];
        int d = r >> 16;
        int p = atomicAdd(&f2[d], 1);
        srt[(off[d] - cnt[d]) + p] = (ushort)(r & 0xFFFFu);
    }
    __syncthreads();

    int grp = tid >> 5, lane = tid & 31;
    int c = lane << 2;
    float s = 1.0f + eps[0];
    for (int dl = grp; dl < 128; dl += 16) {
        int d = b * 128 + dl;
        if (d >= N_NODES) break;
        int st = off[dl] - cnt[dl], cn = cnt[dl];
        s16x4 sv = *(const s16x4*)(xB + (size_t)d * D_IN + c);
        float a0 = bf2f((ushort)sv[0]) * s, a1 = bf2f((ushort)sv[1]) * s,
              a2 = bf2f((ushort)sv[2]) * s, a3 = bf2f((ushort)sv[3]) * s;
        int j = 0;
        for (; j + 3 < cn; j += 4) {
            int s0 = srt[st + j],     s1 = srt[st + j + 1];
            int s2 = srt[st + j + 2], s3 = srt[st + j + 3];
            s16x4 v0 = *(const s16x4*)(xB + (size_t)s0 * D_IN + c);
            s16x4 v1 = *(const s16x4*)(xB + (size_t)s1 * D_IN + c);
            s16x4 v2 = *(const s16x4*)(xB + (size_t)s2 * D_IN + c);
            s16x4 v3 = *(const s16x4*)(xB + (size_t)s3 * D_IN + c);
            a0 += bf2f((ushort)v0[0]) + bf2f((ushort)v1[0]) + bf2f((ushort)v2[0]) + bf2f((ushort)v3[0]);
            a1 += bf2f((ushort)v0[1]) + bf2f((ushort)v1[1]) + bf2f((ushort)v2[1]) + bf2f((ushort)v3[1]);
            a2 += bf2f((ushort)v0[2]) + bf2f((ushort)v1[2]) + bf2f((ushort)v2[2]) + bf2f((ushort)v3[2]);
            a3 += bf2f((ushort)v0[3]) + bf2f((ushort)v1[3]) + bf2f((ushort)v2[3]) + bf2f((ushort)v3[3]);
        }
        for (; j < cn; j++) {
            int s0 = srt[st + j];
            s16x4 v0 = *(const s16x4*)(xB + (size_t)s0 * D_IN + c);
            a0 += bf2f((ushort)v0[0]); a1 += bf2f((ushort)v0[1]);
            a2 += bf2f((ushort)v0[2]); a3 += bf2f((ushort)v0[3]);
        }
        s16x4 o;
        o[0] = (short)f2bf(a0); o[1] = (short)f2bf(a1);
        o[2] = (short)f2bf(a2); o[3] = (short)f2bf(a3);
        *(s16x4*)(h + (size_t)d * D_IN + c) = o;
    }
}

// ================================================================ GEMM1 (MFMA, MT=32 dual-tile): h1B = h @ W1 + BN1 partials
__global__ __launch_bounds__(256) void gemm1_kernel(const ushort* __restrict__ hB,
                                                    const ushort* __restrict__ Wp,
                                                    ushort* __restrict__ h1B,
                                                    float* __restrict__ partial) {
    __shared__ ushort A[MT * D_IN];   // 32x128 bf16 = 8 KB, row stride 256 B, XOR-swizzled
    int tid = threadIdx.x, lane = tid & 63, w = tid >> 6;
    int row0 = blockIdx.x * MT;
    for (int i = tid; i < 512; i += 256) {
        int r = i >> 4, cb = (i & 15) << 4;
        int row = row0 + r;
        s16x8 v = {};
        if (row < N_NODES) v = *(const s16x8*)(hB + (size_t)row * D_IN + (cb >> 1));
        *(s16x8*)((char*)A + r * 256 + (cb ^ ((r & 7) << 4))) = v;
    }
    __syncthreads();
    int m = lane & 15, q = lane >> 4;
    int sw = (m & 7) << 4;               // (m+16)&7 == m&7, same swizzle both tiles
    f32x4 acc[2][4] = {};
    const s16x8* B = (const s16x8*)Wp;
#pragma unroll
    for (int s = 0; s < 4; s++) {
        int co = (s * 64 + q * 16) ^ sw;
        s16x8 a0 = *(const s16x8*)((char*)A + m * 256 + co);
        s16x8 a1 = *(const s16x8*)((char*)A + (m + 16) * 256 + co);
#pragma unroll
        for (int f = 0; f < 4; f++) {
            s16x8 b = B[(s * 16 + w * 4 + f) * 64 + lane];
            acc[0][f] = __builtin_amdgcn_mfma_f32_16x16x32_bf16(a0, b, acc[0][f], 0, 0, 0);
            acc[1][f] = __builtin_amdgcn_mfma_f32_16x16x32_bf16(a1, b, acc[1][f], 0, 0, 0);
        }
    }
#pragma unroll
    for (int f = 0; f < 4; f++) {
        int col = (w * 4 + f) * 16 + m;
        float s1 = 0.f, s2 = 0.f;
#pragma unroll
        for (int t = 0; t < 2; t++) {
#pragma unroll
            for (int j = 0; j < 4; j++) {
                float v = acc[t][f][j];
                int row = row0 + t * 16 + q * 4 + j;
                if (row < N_NODES) h1B[(size_t)row * D_H + col] = f2bf(v);
                s1 += v; s2 = fmaf(v, v, s2);
            }
        }
        s1 += __shfl_xor(s1, 16, 64); s1 += __shfl_xor(s1, 32, 64);
        s2 += __shfl_xor(s2, 16, 64); s2 += __shfl_xor(s2, 32, 64);
        if (lane < 16) {
            partial[(size_t)blockIdx.x * 512 + col] = s1;
            partial[(size_t)blockIdx.x * 512 + 256 + col] = s2;
        }
    }
}

// ================================================================ BN finalize (NPART block-partials)
__global__ __launch_bounds__(256) void bn_finalize_kernel(const float* __restrict__ partial,
                                                          const float* __restrict__ gamma,
                                                          const float* __restrict__ beta,
                                                          float* __restrict__ scale,
                                                          float* __restrict__ shift) {
    int s = blockIdx.x;
    int tid = threadIdx.x;
    float sum = 0.f, sq = 0.f;
    for (int b = tid; b < NPART; b += 256) {
        sum += partial[(size_t)b * 512 + s];
        sq  += partial[(size_t)b * 512 + 256 + s];
    }
    __shared__ float rs[256], rq[256];
    rs[tid] = sum; rq[tid] = sq;
    __syncthreads();
    for (int off = 128; off > 0; off >>= 1) {
        if (tid < off) { rs[tid] += rs[tid + off]; rq[tid] += rq[tid + off]; }
        __syncthreads();
    }
    if (tid == 0) {
        float inv  = 1.0f / (float)N_NODES;
        float mean = rs[0] * inv;
        float var  = rq[0] * inv - mean * mean;
        float sc   = gamma[s] * rsqrtf(var + 1e-5f);
        scale[s] = sc;
        shift[s] = fmaf(-mean, sc, beta[s]);
    }
}

// ================================================================ GEMM2 (MFMA, MT=32 dual-tile): h2B = relu(BN1(h1B)) @ W2 + BN2 partials
__global__ __launch_bounds__(256) void gemm2_kernel(const ushort* __restrict__ h1B,
                                                    const ushort* __restrict__ Wp,
                                                    const float* __restrict__ scale1,
                                                    const float* __restrict__ shift1,
                                                    ushort* __restrict__ h2B,
                                                    float* __restrict__ partial) {
    __shared__ ushort A[MT * D_H];    // 32x256 bf16 = 16 KB, row stride 512 B, swizzled
    int tid = threadIdx.x, lane = tid & 63, w = tid >> 6;
    int row0 = blockIdx.x * MT;
    for (int i = tid; i < 1024; i += 256) {
        int r = i >> 5, cb = (i & 31) << 4;
        int row = row0 + r, c0 = cb >> 1;
        s16x8 o = {};
        if (row < N_NODES) {
            s16x8 in = *(const s16x8*)(h1B + (size_t)row * D_H + c0);
            float4 sc0 = *(const float4*)(scale1 + c0), sc1 = *(const float4*)(scale1 + c0 + 4);
            float4 sh0 = *(const float4*)(shift1 + c0), sh1 = *(const float4*)(shift1 + c0 + 4);
            o[0] = (short)f2bf(fmaxf(fmaf(bf2f((ushort)in[0]), sc0.x, sh0.x), 0.f));
            o[1] = (short)f2bf(fmaxf(fmaf(bf2f((ushort)in[1]), sc0.y, sh0.y), 0.f));
            o[2] = (short)f2bf(fmaxf(fmaf(bf2f((ushort)in[2]), sc0.z, sh0.z), 0.f));
            o[3] = (short)f2bf(fmaxf(fmaf(bf2f((ushort)in[3]), sc0.w, sh0.w), 0.f));
            o[4] = (short)f2bf(fmaxf(fmaf(bf2f((ushort)in[4]), sc1.x, sh1.x), 0.f));
            o[5] = (short)f2bf(fmaxf(fmaf(bf2f((ushort)in[5]), sc1.y, sh1.y), 0.f));
            o[6] = (short)f2bf(fmaxf(fmaf(bf2f((ushort)in[6]), sc1.z, sh1.z), 0.f));
            o[7] = (short)f2bf(fmaxf(fmaf(bf2f((ushort)in[7]), sc1.w, sh1.w), 0.f));
        }
        *(s16x8*)((char*)A + r * 512 + (cb ^ ((r & 7) << 4))) = o;
    }
    __syncthreads();
    int m = lane & 15, q = lane >> 4;
    int sw = (m & 7) << 4;
    f32x4 acc[2][4] = {};
    const s16x8* B = (const s16x8*)Wp;
#pragma unroll
    for (int s = 0; s < 8; s++) {
        int co = (s * 64 + q * 16) ^ sw;
        s16x8 a0 = *(const s16x8*)((char*)A + m * 512 + co);
        s16x8 a1 = *(const s16x8*)((char*)A + (m + 16) * 512 + co);
#pragma unroll
        for (int f = 0; f < 4; f++) {
            s16x8 b = B[(s * 16 + w * 4 + f) * 64 + lane];
            acc[0][f] = __builtin_amdgcn_mfma_f32_16x16x32_bf16(a0, b, acc[0][f], 0, 0, 0);
            acc[1][f] = __builtin_amdgcn_mfma_f32_16x16x32_bf16(a1, b, acc[1][f], 0, 0, 0);
        }
    }
#pragma unroll
    for (int f = 0; f < 4; f++) {
        int col = (w * 4 + f) * 16 + m;
        float s1 = 0.f, s2 = 0.f;
#pragma unroll
        for (int t = 0; t < 2; t++) {
#pragma unroll
            for (int j = 0; j < 4; j++) {
                float v = acc[t][f][j];
                int row = row0 + t * 16 + q * 4 + j;
                if (row < N_NODES) h2B[(size_t)row * D_H + col] = f2bf(v);
                s1 += v; s2 = fmaf(v, v, s2);
            }
        }
        s1 += __shfl_xor(s1, 16, 64); s1 += __shfl_xor(s1, 32, 64);
        s2 += __shfl_xor(s2, 16, 64); s2 += __shfl_xor(s2, 32, 64);
        if (lane < 16) {
            partial[(size_t)blockIdx.x * 512 + col] = s1;
            partial[(size_t)blockIdx.x * 512 + 256 + col] = s2;
        }
    }
}

// ================================================================ final: out = relu(BN2(h2B)) -> fp32
__global__ __launch_bounds__(256) void bn2_apply_kernel(const ushort* __restrict__ h2B,
                                                        const float* __restrict__ scale,
                                                        const float* __restrict__ shift,
                                                        float* __restrict__ out, int total8) {
    int i = blockIdx.x * 256 + threadIdx.x;
    if (i >= total8) return;
    s16x8 v = ((const s16x8*)h2B)[i];
    int c = (i & 31) << 3;
    float4 sc0 = *(const float4*)(scale + c), sc1 = *(const float4*)(scale + c + 4);
    float4 sh0 = *(const float4*)(shift + c), sh1 = *(const float4*)(shift + c + 4);
    float4 o0, o1;
    o0.x = fmaxf(fmaf(bf2f((ushort)v[0]), sc0.x, sh0.x), 0.f);
    o0.y = fmaxf(fmaf(bf2f((ushort)v[1]), sc0.y, sh0.y), 0.f);
    o0.z = fmaxf(fmaf(bf2f((ushort)v[2]), sc0.z, sh0.z), 0.f);
    o0.w = fmaxf(fmaf(bf2f((ushort)v[3]), sc0.w, sh0.w), 0.f);
    o1.x = fmaxf(fmaf(bf2f((ushort)v[4]), sc1.x, sh1.x), 0.f);
    o1.y = fmaxf(fmaf(bf2f((ushort)v[5]), sc1.y, sh1.y), 0.f);
    o1.z = fmaxf(fmaf(bf2f((ushort)v[6]), sc1.z, sh1.z), 0.f);
    o1.w = fmaxf(fmaf(bf2f((ushort)v[7]), sc1.w, sh1.w), 0.f);
    ((float4*)out)[(size_t)i * 2]     = o0;
    ((float4*)out)[(size_t)i * 2 + 1] = o1;
}

// ================================================================
extern "C" void kernel_launch(void* const* d_in, const int* in_sizes, int n_in,
                              void* d_out, int out_size, void* d_ws, size_t ws_size,
                              hipStream_t stream) {
    const float* x      = (const float*)d_in[0];
    const int*   ei     = (const int*)d_in[1];
    const float* eps    = (const float*)d_in[3];
    const float* W1     = (const float*)d_in[4];
    const float* gamma1 = (const float*)d_in[5];
    const float* beta1  = (const float*)d_in[6];
    const float* W2     = (const float*)d_in[7];
    const float* gamma2 = (const float*)d_in[8];
    const float* beta2  = (const float*)d_in[9];
    int E = in_sizes[1] / 2;

    char* ws = (char*)d_ws;
    ushort* xB     = (ushort*)(ws);                 // 12,800,000 B (dead after gather)
    float*  partial= (float*)(ws);                  // 3,201,024 B  (overlaps xB; live from gemm1)
    ushort* hB     = (ushort*)(ws + 12800000);      // 12,800,000 B
    ushort* h1B    = (ushort*)(ws + 25600000);      // 25,600,000 B
    ushort* h2B    = (ushort*)(ws + 51200000);      // 25,600,000 B (overlaps bucket scratch)
    float*  stats  = (float*)(ws + 76800000);       // 4,096 B
    ushort* Wp1    = (ushort*)(ws + 76804096);      // 65,536 B
    ushort* Wp2    = (ushort*)(ws + 76869632);      // 131,072 B -> end 77,000,704
    float* scale1 = stats, *shift1 = stats + 256, *scale2 = stats + 512, *shift2 = stats + 768;
    float* out = (float*)d_out;

    int*  bucket_fill = (int*)(ws + 51200000);      // 391*4 -> pad 2048
    uint* bucket_buf  = (uint*)(ws + 51202048);     // 391*3072*4 = 4,804,608 B

    prep_kernel<<<3174, 256, 0, stream>>>(x, W1, W2, xB, Wp1, Wp2, bucket_fill);
    bucket_kernel<<<(E + EPB - 1) / EPB, 256, 0, stream>>>(ei, bucket_fill, bucket_buf, E);
    gather_bucket_kernel<<<NBKT, 512, 0, stream>>>(xB, eps, bucket_fill, bucket_buf, hB);

    gemm1_kernel<<<NGB, 256, 0, stream>>>(hB, Wp1, h1B, partial);
    bn_finalize_kernel<<<D_H, 256, 0, stream>>>(partial, gamma1, beta1, scale1, shift1);
    gemm2_kernel<<<NGB, 256, 0, stream>>>(h1B, Wp2, scale1, shift1, h2B, partial);
    bn_finalize_kernel<<<D_H, 256, 0, stream>>>(partial, gamma2, beta2, scale2, shift2);
    bn2_apply_kernel<<<(1600000 + 255) / 256, 256, 0, stream>>>(h2B, scale2, shift2, out, 1600000);
}

// Round 13
// 132.524 us; speedup vs baseline: 1.3697x; 1.0205x over previous
//
#include <hip/hip_runtime.h>

#define N_NODES 50000
#define D_IN    128
#define D_H     256
#define MT      64
#define NGB     782                      // ceil(50000/64), tail block has 16 rows
#define NPART   NGB

#define NBKT    391                      // ceil(50000/128) dst-buckets of 128 nodes
#define BKT_CAP 3072                     // mean 2046 + 23 sigma for uniform edges
#define EPB     2048                     // edges per bucket_kernel block (391 blocks)

typedef short s16x8 __attribute__((ext_vector_type(8)));
typedef short s16x4 __attribute__((ext_vector_type(4)));
typedef float f32x4 __attribute__((ext_vector_type(4)));

__device__ inline ushort f2bf(float f) {           // RNE fp32->bf16
    uint u = __float_as_uint(f);
    return (ushort)((u + 0x7FFFu + ((u >> 16) & 1u)) >> 16);
}
__device__ inline float bf2f(ushort u) { return __uint_as_float(((uint)u) << 16); }

// ================================================================ fused prep: cvt_x | pack_w | zero bucket_fill
__global__ __launch_bounds__(256) void prep_kernel(const float* __restrict__ x,
                                                   const float* __restrict__ W1,
                                                   const float* __restrict__ W2,
                                                   ushort* __restrict__ xB,
                                                   ushort* __restrict__ Wp1,
                                                   ushort* __restrict__ Wp2,
                                                   int* __restrict__ bucket_fill) {
    int bid = blockIdx.x, tid = threadIdx.x;
    if (bid < 3125) {
        int i = bid * 256 + tid;                    // < 800000
        float4 a = ((const float4*)x)[(size_t)i * 2];
        float4 b = ((const float4*)x)[(size_t)i * 2 + 1];
        s16x8 o;
        o[0] = (short)f2bf(a.x); o[1] = (short)f2bf(a.y);
        o[2] = (short)f2bf(a.z); o[3] = (short)f2bf(a.w);
        o[4] = (short)f2bf(b.x); o[5] = (short)f2bf(b.y);
        o[6] = (short)f2bf(b.z); o[7] = (short)f2bf(b.w);
        ((s16x8*)xB)[i] = o;
    } else if (bid < 3173) {
        int t = (bid - 3125) * 256 + tid;
        const float* W; ushort* Wp; int u;
        if (t < 4096) { W = W1; Wp = Wp1; u = t; }
        else          { W = W2; Wp = Wp2; u = t - 4096; }
        int l = u & 63, gs = u >> 6;
        int g = gs & 15, s = gs >> 4;
        int col = g * 16 + (l & 15), q = l >> 4;
        s16x8 o;
#pragma unroll
        for (int j = 0; j < 8; j++) {
            int k = s * 32 + q * 8 + j;
            o[j] = (short)f2bf(W[(size_t)k * D_H + col]);
        }
        *(s16x8*)(Wp + (size_t)u * 8) = o;
    } else {
        for (int i = tid; i < NBKT; i += 256) bucket_fill[i] = 0;
    }
}

// ================================================================ pass A: bucket edges by dst>>7
__global__ __launch_bounds__(256) void bucket_kernel(const int* __restrict__ ei,
                                                     int* __restrict__ bucket_fill,
                                                     uint* __restrict__ bucket_buf, int E) {
    __shared__ int cnt[NBKT], gbase[NBKT], fill2[NBKT];
    int tid = threadIdx.x;
    int e0 = blockIdx.x * EPB;
    for (int i = tid; i < NBKT; i += 256) { cnt[i] = 0; fill2[i] = 0; }
    __syncthreads();
    int dstv[8];
#pragma unroll
    for (int j = 0; j < 8; j++) {
        int e = e0 + j * 256 + tid;
        dstv[j] = (e < E) ? ei[E + e] : -1;
        if (dstv[j] >= 0) atomicAdd(&cnt[dstv[j] >> 7], 1);
    }
    __syncthreads();
    for (int i = tid; i < NBKT; i += 256) {
        int c = cnt[i];
        gbase[i] = c ? atomicAdd(&bucket_fill[i], c) : 0;
    }
    __syncthreads();
#pragma unroll
    for (int j = 0; j < 8; j++) {
        int e = e0 + j * 256 + tid;
        if (dstv[j] >= 0) {
            int src = ei[e];
            int b = dstv[j] >> 7;
            int p = atomicAdd(&fill2[b], 1);
            bucket_buf[(size_t)b * BKT_CAP + gbase[b] + p] =
                ((uint)(dstv[j] & 127) << 16) | (uint)src;
        }
    }
}

// ================================================================ pass B: per-bucket LDS counting sort + gather
__global__ __launch_bounds__(512) void gather_bucket_kernel(const ushort* __restrict__ xB,
                                                            const float* __restrict__ eps,
                                                            const int* __restrict__ bucket_fill,
                                                            const uint* __restrict__ bucket_buf,
                                                            ushort* __restrict__ h) {
    __shared__ uint   raw[BKT_CAP];
    __shared__ ushort srt[BKT_CAP];
    __shared__ int cnt[128], off[128], f2[128];
    int b = blockIdx.x, tid = threadIdx.x;
    int n = bucket_fill[b];
    if (n > BKT_CAP) n = BKT_CAP;
    for (int i = tid; i < n; i += 512) raw[i] = bucket_buf[(size_t)b * BKT_CAP + i];
    if (tid < 128) { cnt[tid] = 0; f2[tid] = 0; }
    __syncthreads();
    for (int i = tid; i < n; i += 512) atomicAdd(&cnt[raw[i] >> 16], 1);
    __syncthreads();
    if (tid < 128) off[tid] = cnt[tid];
    __syncthreads();
    for (int s2 = 1; s2 < 128; s2 <<= 1) {
        int t = (tid < 128 && tid >= s2) ? off[tid - s2] : 0;
        __syncthreads();
        if (tid < 128) off[tid] += t;
        __syncthreads();
    }
    for (int i = tid; i < n; i += 512) {
        uint r = raw[i];
        int d = r >> 16;
        int p = atomicAdd(&f2[d], 1);
        srt[(off[d] - cnt[d]) + p] = (ushort)(r & 0xFFFFu);
    }
    __syncthreads();

    int grp = tid >> 5, lane = tid & 31;
    int c = lane << 2;
    float s = 1.0f + eps[0];
    for (int dl = grp; dl < 128; dl += 16) {
        int d = b * 128 + dl;
        if (d >= N_NODES) break;
        int st = off[dl] - cnt[dl], cn = cnt[dl];
        s16x4 sv = *(const s16x4*)(xB + (size_t)d * D_IN + c);
        float a0 = bf2f((ushort)sv[0]) * s, a1 = bf2f((ushort)sv[1]) * s,
              a2 = bf2f((ushort)sv[2]) * s, a3 = bf2f((ushort)sv[3]) * s;
        int j = 0;
        for (; j + 3 < cn; j += 4) {
            int s0 = srt[st + j],     s1 = srt[st + j + 1];
            int s2 = srt[st + j + 2], s3 = srt[st + j + 3];
            s16x4 v0 = *(const s16x4*)(xB + (size_t)s0 * D_IN + c);
            s16x4 v1 = *(const s16x4*)(xB + (size_t)s1 * D_IN + c);
            s16x4 v2 = *(const s16x4*)(xB + (size_t)s2 * D_IN + c);
            s16x4 v3 = *(const s16x4*)(xB + (size_t)s3 * D_IN + c);
            a0 += bf2f((ushort)v0[0]) + bf2f((ushort)v1[0]) + bf2f((ushort)v2[0]) + bf2f((ushort)v3[0]);
            a1 += bf2f((ushort)v0[1]) + bf2f((ushort)v1[1]) + bf2f((ushort)v2[1]) + bf2f((ushort)v3[1]);
            a2 += bf2f((ushort)v0[2]) + bf2f((ushort)v1[2]) + bf2f((ushort)v2[2]) + bf2f((ushort)v3[2]);
            a3 += bf2f((ushort)v0[3]) + bf2f((ushort)v1[3]) + bf2f((ushort)v2[3]) + bf2f((ushort)v3[3]);
        }
        for (; j < cn; j++) {
            int s0 = srt[st + j];
            s16x4 v0 = *(const s16x4*)(xB + (size_t)s0 * D_IN + c);
            a0 += bf2f((ushort)v0[0]); a1 += bf2f((ushort)v0[1]);
            a2 += bf2f((ushort)v0[2]); a3 += bf2f((ushort)v0[3]);
        }
        s16x4 o;
        o[0] = (short)f2bf(a0); o[1] = (short)f2bf(a1);
        o[2] = (short)f2bf(a2); o[3] = (short)f2bf(a3);
        *(s16x4*)(h + (size_t)d * D_IN + c) = o;
    }
}

// ================================================================ GEMM1 (MFMA, MT=64 quad-tile): h1B = h @ W1 + BN1 partials
__global__ __launch_bounds__(256) void gemm1_kernel(const ushort* __restrict__ hB,
                                                    const ushort* __restrict__ Wp,
                                                    ushort* __restrict__ h1B,
                                                    float* __restrict__ partial) {
    __shared__ ushort A[MT * D_IN];   // 64x128 bf16 = 16 KB, row stride 256 B, XOR-swizzled
    int tid = threadIdx.x, lane = tid & 63, w = tid >> 6;
    int row0 = blockIdx.x * MT;
    for (int i = tid; i < 1024; i += 256) {
        int r = i >> 4, cb = (i & 15) << 4;
        int row = row0 + r;
        s16x8 v = {};
        if (row < N_NODES) v = *(const s16x8*)(hB + (size_t)row * D_IN + (cb >> 1));
        *(s16x8*)((char*)A + r * 256 + (cb ^ ((r & 7) << 4))) = v;
    }
    __syncthreads();
    int m = lane & 15, q = lane >> 4;
    int sw = (m & 7) << 4;               // (m+16k)&7 == m&7: same swizzle all four tiles
    f32x4 acc[4][4] = {};
    const s16x8* B = (const s16x8*)Wp;
#pragma unroll
    for (int s = 0; s < 4; s++) {
        int co = (s * 64 + q * 16) ^ sw;
        s16x8 a0 = *(const s16x8*)((char*)A + (m     ) * 256 + co);
        s16x8 a1 = *(const s16x8*)((char*)A + (m + 16) * 256 + co);
        s16x8 a2 = *(const s16x8*)((char*)A + (m + 32) * 256 + co);
        s16x8 a3 = *(const s16x8*)((char*)A + (m + 48) * 256 + co);
#pragma unroll
        for (int f = 0; f < 4; f++) {
            s16x8 b = B[(s * 16 + w * 4 + f) * 64 + lane];
            acc[0][f] = __builtin_amdgcn_mfma_f32_16x16x32_bf16(a0, b, acc[0][f], 0, 0, 0);
            acc[1][f] = __builtin_amdgcn_mfma_f32_16x16x32_bf16(a1, b, acc[1][f], 0, 0, 0);
            acc[2][f] = __builtin_amdgcn_mfma_f32_16x16x32_bf16(a2, b, acc[2][f], 0, 0, 0);
            acc[3][f] = __builtin_amdgcn_mfma_f32_16x16x32_bf16(a3, b, acc[3][f], 0, 0, 0);
        }
    }
#pragma unroll
    for (int f = 0; f < 4; f++) {
        int col = (w * 4 + f) * 16 + m;
        float s1 = 0.f, s2 = 0.f;
#pragma unroll
        for (int t = 0; t < 4; t++) {
#pragma unroll
            for (int j = 0; j < 4; j++) {
                float v = acc[t][f][j];
                int row = row0 + t * 16 + q * 4 + j;
                if (row < N_NODES) h1B[(size_t)row * D_H + col] = f2bf(v);
                s1 += v; s2 = fmaf(v, v, s2);
            }
        }
        s1 += __shfl_xor(s1, 16, 64); s1 += __shfl_xor(s1, 32, 64);
        s2 += __shfl_xor(s2, 16, 64); s2 += __shfl_xor(s2, 32, 64);
        if (lane < 16) {
            partial[(size_t)blockIdx.x * 512 + col] = s1;
            partial[(size_t)blockIdx.x * 512 + 256 + col] = s2;
        }
    }
}

// ================================================================ BN finalize (NPART block-partials)
__global__ __launch_bounds__(256) void bn_finalize_kernel(const float* __restrict__ partial,
                                                          const float* __restrict__ gamma,
                                                          const float* __restrict__ beta,
                                                          float* __restrict__ scale,
                                                          float* __restrict__ shift) {
    int s = blockIdx.x;
    int tid = threadIdx.x;
    float sum = 0.f, sq = 0.f;
    for (int b = tid; b < NPART; b += 256) {
        sum += partial[(size_t)b * 512 + s];
        sq  += partial[(size_t)b * 512 + 256 + s];
    }
    __shared__ float rs[256], rq[256];
    rs[tid] = sum; rq[tid] = sq;
    __syncthreads();
    for (int off = 128; off > 0; off >>= 1) {
        if (tid < off) { rs[tid] += rs[tid + off]; rq[tid] += rq[tid + off]; }
        __syncthreads();
    }
    if (tid == 0) {
        float inv  = 1.0f / (float)N_NODES;
        float mean = rs[0] * inv;
        float var  = rq[0] * inv - mean * mean;
        float sc   = gamma[s] * rsqrtf(var + 1e-5f);
        scale[s] = sc;
        shift[s] = fmaf(-mean, sc, beta[s]);
    }
}

// ================================================================ GEMM2 (MFMA, MT=64 quad-tile): h2B = relu(BN1(h1B)) @ W2 + BN2 partials
__global__ __launch_bounds__(256) void gemm2_kernel(const ushort* __restrict__ h1B,
                                                    const ushort* __restrict__ Wp,
                                                    const float* __restrict__ scale1,
                                                    const float* __restrict__ shift1,
                                                    ushort* __restrict__ h2B,
                                                    float* __restrict__ partial) {
    __shared__ ushort A[MT * D_H];    // 64x256 bf16 = 32 KB, row stride 512 B, swizzled
    int tid = threadIdx.x, lane = tid & 63, w = tid >> 6;
    int row0 = blockIdx.x * MT;
    for (int i = tid; i < 2048; i += 256) {
        int r = i >> 5, cb = (i & 31) << 4;
        int row = row0 + r, c0 = cb >> 1;
        s16x8 o = {};
        if (row < N_NODES) {
            s16x8 in = *(const s16x8*)(h1B + (size_t)row * D_H + c0);
            float4 sc0 = *(const float4*)(scale1 + c0), sc1 = *(const float4*)(scale1 + c0 + 4);
            float4 sh0 = *(const float4*)(shift1 + c0), sh1 = *(const float4*)(shift1 + c0 + 4);
            o[0] = (short)f2bf(fmaxf(fmaf(bf2f((ushort)in[0]), sc0.x, sh0.x), 0.f));
            o[1] = (short)f2bf(fmaxf(fmaf(bf2f((ushort)in[1]), sc0.y, sh0.y), 0.f));
            o[2] = (short)f2bf(fmaxf(fmaf(bf2f((ushort)in[2]), sc0.z, sh0.z), 0.f));
            o[3] = (short)f2bf(fmaxf(fmaf(bf2f((ushort)in[3]), sc0.w, sh0.w), 0.f));
            o[4] = (short)f2bf(fmaxf(fmaf(bf2f((ushort)in[4]), sc1.x, sh1.x), 0.f));
            o[5] = (short)f2bf(fmaxf(fmaf(bf2f((ushort)in[5]), sc1.y, sh1.y), 0.f));
            o[6] = (short)f2bf(fmaxf(fmaf(bf2f((ushort)in[6]), sc1.z, sh1.z), 0.f));
            o[7] = (short)f2bf(fmaxf(fmaf(bf2f((ushort)in[7]), sc1.w, sh1.w), 0.f));
        }
        *(s16x8*)((char*)A + r * 512 + (cb ^ ((r & 7) << 4))) = o;
    }
    __syncthreads();
    int m = lane & 15, q = lane >> 4;
    int sw = (m & 7) << 4;
    f32x4 acc[4][4] = {};
    const s16x8* B = (const s16x8*)Wp;
#pragma unroll
    for (int s = 0; s < 8; s++) {
        int co = (s * 64 + q * 16) ^ sw;
        s16x8 a0 = *(const s16x8*)((char*)A + (m     ) * 512 + co);
        s16x8 a1 = *(const s16x8*)((char*)A + (m + 16) * 512 + co);
        s16x8 a2 = *(const s16x8*)((char*)A + (m + 32) * 512 + co);
        s16x8 a3 = *(const s16x8*)((char*)A + (m + 48) * 512 + co);
#pragma unroll
        for (int f = 0; f < 4; f++) {
            s16x8 b = B[(s * 16 + w * 4 + f) * 64 + lane];
            acc[0][f] = __builtin_amdgcn_mfma_f32_16x16x32_bf16(a0, b, acc[0][f], 0, 0, 0);
            acc[1][f] = __builtin_amdgcn_mfma_f32_16x16x32_bf16(a1, b, acc[1][f], 0, 0, 0);
            acc[2][f] = __builtin_amdgcn_mfma_f32_16x16x32_bf16(a2, b, acc[2][f], 0, 0, 0);
            acc[3][f] = __builtin_amdgcn_mfma_f32_16x16x32_bf16(a3, b, acc[3][f], 0, 0, 0);
        }
    }
#pragma unroll
    for (int f = 0; f < 4; f++) {
        int col = (w * 4 + f) * 16 + m;
        float s1 = 0.f, s2 = 0.f;
#pragma unroll
        for (int t = 0; t < 4; t++) {
#pragma unroll
            for (int j = 0; j < 4; j++) {
                float v = acc[t][f][j];
                int row = row0 + t * 16 + q * 4 + j;
                if (row < N_NODES) h2B[(size_t)row * D_H + col] = f2bf(v);
                s1 += v; s2 = fmaf(v, v, s2);
            }
        }
        s1 += __shfl_xor(s1, 16, 64); s1 += __shfl_xor(s1, 32, 64);
        s2 += __shfl_xor(s2, 16, 64); s2 += __shfl_xor(s2, 32, 64);
        if (lane < 16) {
            partial[(size_t)blockIdx.x * 512 + col] = s1;
            partial[(size_t)blockIdx.x * 512 + 256 + col] = s2;
        }
    }
}

// ================================================================ final: out = relu(BN2(h2B)) -> fp32
__global__ __launch_bounds__(256) void bn2_apply_kernel(const ushort* __restrict__ h2B,
                                                        const float* __restrict__ scale,
                                                        const float* __restrict__ shift,
                                                        float* __restrict__ out, int total8) {
    int i = blockIdx.x * 256 + threadIdx.x;
    if (i >= total8) return;
    s16x8 v = ((const s16x8*)h2B)[i];
    int c = (i & 31) << 3;
    float4 sc0 = *(const float4*)(scale + c), sc1 = *(const float4*)(scale + c + 4);
    float4 sh0 = *(const float4*)(shift + c), sh1 = *(const float4*)(shift + c + 4);
    float4 o0, o1;
    o0.x = fmaxf(fmaf(bf2f((ushort)v[0]), sc0.x, sh0.x), 0.f);
    o0.y = fmaxf(fmaf(bf2f((ushort)v[1]), sc0.y, sh0.y), 0.f);
    o0.z = fmaxf(fmaf(bf2f((ushort)v[2]), sc0.z, sh0.z), 0.f);
    o0.w = fmaxf(fmaf(bf2f((ushort)v[3]), sc0.w, sh0.w), 0.f);
    o1.x = fmaxf(fmaf(bf2f((ushort)v[4]), sc1.x, sh1.x), 0.f);
    o1.y = fmaxf(fmaf(bf2f((ushort)v[5]), sc1.y, sh1.y), 0.f);
    o1.z = fmaxf(fmaf(bf2f((ushort)v[6]), sc1.z, sh1.z), 0.f);
    o1.w = fmaxf(fmaf(bf2f((ushort)v[7]), sc1.w, sh1.w), 0.f);
    ((float4*)out)[(size_t)i * 2]     = o0;
    ((float4*)out)[(size_t)i * 2 + 1] = o1;
}

// ================================================================
extern "C" void kernel_launch(void* const* d_in, const int* in_sizes, int n_in,
                              void* d_out, int out_size, void* d_ws, size_t ws_size,
                              hipStream_t stream) {
    const float* x      = (const float*)d_in[0];
    const int*   ei     = (const int*)d_in[1];
    const float* eps    = (const float*)d_in[3];
    const float* W1     = (const float*)d_in[4];
    const float* gamma1 = (const float*)d_in[5];
    const float* beta1  = (const float*)d_in[6];
    const float* W2     = (const float*)d_in[7];
    const float* gamma2 = (const float*)d_in[8];
    const float* beta2  = (const float*)d_in[9];
    int E = in_sizes[1] / 2;

    char* ws = (char*)d_ws;
    ushort* xB     = (ushort*)(ws);                 // 12,800,000 B (dead after gather)
    float*  partial= (float*)(ws);                  // 1,601,536 B  (overlaps xB; live from gemm1)
    ushort* hB     = (ushort*)(ws + 12800000);      // 12,800,000 B
    ushort* h1B    = (ushort*)(ws + 25600000);      // 25,600,000 B
    ushort* h2B    = (ushort*)(ws + 51200000);      // 25,600,000 B (overlaps bucket scratch)
    float*  stats  = (float*)(ws + 76800000);       // 4,096 B
    ushort* Wp1    = (ushort*)(ws + 76804096);      // 65,536 B
    ushort* Wp2    = (ushort*)(ws + 76869632);      // 131,072 B -> end 77,000,704
    float* scale1 = stats, *shift1 = stats + 256, *scale2 = stats + 512, *shift2 = stats + 768;
    float* out = (float*)d_out;

    int*  bucket_fill = (int*)(ws + 51200000);      // 391*4 -> pad 2048
    uint* bucket_buf  = (uint*)(ws + 51202048);     // 391*3072*4 = 4,804,608 B

    prep_kernel<<<3174, 256, 0, stream>>>(x, W1, W2, xB, Wp1, Wp2, bucket_fill);
    bucket_kernel<<<(E + EPB - 1) / EPB, 256, 0, stream>>>(ei, bucket_fill, bucket_buf, E);
    gather_bucket_kernel<<<NBKT, 512, 0, stream>>>(xB, eps, bucket_fill, bucket_buf, hB);

    gemm1_kernel<<<NGB, 256, 0, stream>>>(hB, Wp1, h1B, partial);
    bn_finalize_kernel<<<D_H, 256, 0, stream>>>(partial, gamma1, beta1, scale1, shift1);
    gemm2_kernel<<<NGB, 256, 0, stream>>>(h1B, Wp2, scale1, shift1, h2B, partial);
    bn_finalize_kernel<<<D_H, 256, 0, stream>>>(partial, gamma2, beta2, scale2, shift2);
    bn2_apply_kernel<<<(1600000 + 255) / 256, 256, 0, stream>>>(h2B, scale2, shift2, out, 1600000);
}

// Round 14
// 121.448 us; speedup vs baseline: 1.4946x; 1.0912x over previous
//
#include <hip/hip_runtime.h>

#define N_NODES 50000
#define D_IN    128
#define D_H     256
#define MT      64
#define NGB     782                      // ceil(50000/64), tail block has 16 rows
#define NPART   NGB

#define NBKT    391                      // ceil(50000/128) dst-buckets of 128 nodes
#define BKT_CAP 3072                     // mean 2046 + 23 sigma for uniform edges
#define EPB     2048                     // edges per bucket_kernel block (391 blocks)

typedef short s16x8 __attribute__((ext_vector_type(8)));
typedef short s16x4 __attribute__((ext_vector_type(4)));
typedef float f32x4 __attribute__((ext_vector_type(4)));

__device__ inline ushort f2bf(float f) {           // RNE fp32->bf16
    uint u = __float_as_uint(f);
    return (ushort)((u + 0x7FFFu + ((u >> 16) & 1u)) >> 16);
}
__device__ inline float bf2f(ushort u) { return __uint_as_float(((uint)u) << 16); }

// ================================================================ fused prep: cvt_x | pack_w | zero bucket_fill
__global__ __launch_bounds__(256) void prep_kernel(const float* __restrict__ x,
                                                   const float* __restrict__ W1,
                                                   const float* __restrict__ W2,
                                                   ushort* __restrict__ xB,
                                                   ushort* __restrict__ Wp1,
                                                   ushort* __restrict__ Wp2,
                                                   int* __restrict__ bucket_fill) {
    int bid = blockIdx.x, tid = threadIdx.x;
    if (bid < 3125) {
        int i = bid * 256 + tid;                    // < 800000
        float4 a = ((const float4*)x)[(size_t)i * 2];
        float4 b = ((const float4*)x)[(size_t)i * 2 + 1];
        s16x8 o;
        o[0] = (short)f2bf(a.x); o[1] = (short)f2bf(a.y);
        o[2] = (short)f2bf(a.z); o[3] = (short)f2bf(a.w);
        o[4] = (short)f2bf(b.x); o[5] = (short)f2bf(b.y);
        o[6] = (short)f2bf(b.z); o[7] = (short)f2bf(b.w);
        ((s16x8*)xB)[i] = o;
    } else if (bid < 3173) {
        int t = (bid - 3125) * 256 + tid;
        const float* W; ushort* Wp; int u;
        if (t < 4096) { W = W1; Wp = Wp1; u = t; }
        else          { W = W2; Wp = Wp2; u = t - 4096; }
        int l = u & 63, gs = u >> 6;
        int g = gs & 15, s = gs >> 4;
        int col = g * 16 + (l & 15), q = l >> 4;
        s16x8 o;
#pragma unroll
        for (int j = 0; j < 8; j++) {
            int k = s * 32 + q * 8 + j;
            o[j] = (short)f2bf(W[(size_t)k * D_H + col]);
        }
        *(s16x8*)(Wp + (size_t)u * 8) = o;
    } else {
        for (int i = tid; i < NBKT; i += 256) bucket_fill[i] = 0;
    }
}

// ================================================================ pass A: bucket edges by dst>>7
__global__ __launch_bounds__(256) void bucket_kernel(const int* __restrict__ ei,
                                                     int* __restrict__ bucket_fill,
                                                     uint* __restrict__ bucket_buf, int E) {
    __shared__ int cnt[NBKT], gbase[NBKT], fill2[NBKT];
    int tid = threadIdx.x;
    int e0 = blockIdx.x * EPB;
    for (int i = tid; i < NBKT; i += 256) { cnt[i] = 0; fill2[i] = 0; }
    __syncthreads();
    int dstv[8];
#pragma unroll
    for (int j = 0; j < 8; j++) {
        int e = e0 + j * 256 + tid;
        dstv[j] = (e < E) ? ei[E + e] : -1;
        if (dstv[j] >= 0) atomicAdd(&cnt[dstv[j] >> 7], 1);
    }
    __syncthreads();
    for (int i = tid; i < NBKT; i += 256) {
        int c = cnt[i];
        gbase[i] = c ? atomicAdd(&bucket_fill[i], c) : 0;
    }
    __syncthreads();
#pragma unroll
    for (int j = 0; j < 8; j++) {
        int e = e0 + j * 256 + tid;
        if (dstv[j] >= 0) {
            int src = ei[e];
            int b = dstv[j] >> 7;
            int p = atomicAdd(&fill2[b], 1);
            bucket_buf[(size_t)b * BKT_CAP + gbase[b] + p] =
                ((uint)(dstv[j] & 127) << 16) | (uint)src;
        }
    }
}

// ================================================================ pass B: per-bucket LDS counting sort + gather
__global__ __launch_bounds__(512) void gather_bucket_kernel(const ushort* __restrict__ xB,
                                                            const float* __restrict__ eps,
                                                            const int* __restrict__ bucket_fill,
                                                            const uint* __restrict__ bucket_buf,
                                                            ushort* __restrict__ h) {
    __shared__ uint   raw[BKT_CAP];
    __shared__ ushort srt[BKT_CAP];
    __shared__ int cnt[128], off[128], f2[128];
    int b = blockIdx.x, tid = threadIdx.x;
    int n = bucket_fill[b];
    if (n > BKT_CAP) n = BKT_CAP;
    for (int i = tid; i < n; i += 512) raw[i] = bucket_buf[(size_t)b * BKT_CAP + i];
    if (tid < 128) { cnt[tid] = 0; f2[tid] = 0; }
    __syncthreads();
    for (int i = tid; i < n; i += 512) atomicAdd(&cnt[raw[i] >> 16], 1);
    __syncthreads();
    if (tid < 128) off[tid] = cnt[tid];
    __syncthreads();
    for (int s2 = 1; s2 < 128; s2 <<= 1) {
        int t = (tid < 128 && tid >= s2) ? off[tid - s2] : 0;
        __syncthreads();
        if (tid < 128) off[tid] += t;
        __syncthreads();
    }
    for (int i = tid; i < n; i += 512) {
        uint r = raw[i];
        int d = r >> 16;
        int p = atomicAdd(&f2[d], 1);
        srt[(off[d] - cnt[d]) + p] = (ushort)(r & 0xFFFFu);
    }
    __syncthreads();

    int grp = tid >> 5, lane = tid & 31;
    int c = lane << 2;
    float s = 1.0f + eps[0];
    for (int dl = grp; dl < 128; dl += 16) {
        int d = b * 128 + dl;
        if (d >= N_NODES) break;
        int st = off[dl] - cnt[dl], cn = cnt[dl];
        s16x4 sv = *(const s16x4*)(xB + (size_t)d * D_IN + c);
        float a0 = bf2f((ushort)sv[0]) * s, a1 = bf2f((ushort)sv[1]) * s,
              a2 = bf2f((ushort)sv[2]) * s, a3 = bf2f((ushort)sv[3]) * s;
        int j = 0;
        for (; j + 3 < cn; j += 4) {
            int s0 = srt[st + j],     s1 = srt[st + j + 1];
            int s2 = srt[st + j + 2], s3 = srt[st + j + 3];
            s16x4 v0 = *(const s16x4*)(xB + (size_t)s0 * D_IN + c);
            s16x4 v1 = *(const s16x4*)(xB + (size_t)s1 * D_IN + c);
            s16x4 v2 = *(const s16x4*)(xB + (size_t)s2 * D_IN + c);
            s16x4 v3 = *(const s16x4*)(xB + (size_t)s3 * D_IN + c);
            a0 += bf2f((ushort)v0[0]) + bf2f((ushort)v1[0]) + bf2f((ushort)v2[0]) + bf2f((ushort)v3[0]);
            a1 += bf2f((ushort)v0[1]) + bf2f((ushort)v1[1]) + bf2f((ushort)v2[1]) + bf2f((ushort)v3[1]);
            a2 += bf2f((ushort)v0[2]) + bf2f((ushort)v1[2]) + bf2f((ushort)v2[2]) + bf2f((ushort)v3[2]);
            a3 += bf2f((ushort)v0[3]) + bf2f((ushort)v1[3]) + bf2f((ushort)v2[3]) + bf2f((ushort)v3[3]);
        }
        for (; j < cn; j++) {
            int s0 = srt[st + j];
            s16x4 v0 = *(const s16x4*)(xB + (size_t)s0 * D_IN + c);
            a0 += bf2f((ushort)v0[0]); a1 += bf2f((ushort)v0[1]);
            a2 += bf2f((ushort)v0[2]); a3 += bf2f((ushort)v0[3]);
        }
        s16x4 o;
        o[0] = (short)f2bf(a0); o[1] = (short)f2bf(a1);
        o[2] = (short)f2bf(a2); o[3] = (short)f2bf(a3);
        *(s16x4*)(h + (size_t)d * D_IN + c) = o;
    }
}

// ================================================================ GEMM1 (MFMA, MT=64, 8 waves, B-in-registers): h1B = h @ W1 + BN1 partials
__global__ __launch_bounds__(512) void gemm1_kernel(const ushort* __restrict__ hB,
                                                    const ushort* __restrict__ Wp,
                                                    ushort* __restrict__ h1B,
                                                    float* __restrict__ partial) {
    __shared__ ushort A[MT * D_IN];   // 64x128 bf16 = 16 KB, row stride 256 B, XOR-swizzled
    int tid = threadIdx.x, lane = tid & 63, w = tid >> 6;   // w in 0..7: col-groups {2w, 2w+1}
    int row0 = blockIdx.x * MT;
    int m = lane & 15, q = lane >> 4;
    const s16x8* B = (const s16x8*)Wp;
    // preload this wave's full B slice: 4 s-steps x 2 col-groups = 8 frags (32 VGPR)
    s16x8 bf[8];
#pragma unroll
    for (int s = 0; s < 4; s++)
#pragma unroll
        for (int f = 0; f < 2; f++)
            bf[s * 2 + f] = B[(s * 16 + w * 2 + f) * 64 + lane];
    // stage A
    for (int i = tid; i < 1024; i += 512) {
        int r = i >> 4, cb = (i & 15) << 4;
        int row = row0 + r;
        s16x8 v = {};
        if (row < N_NODES) v = *(const s16x8*)(hB + (size_t)row * D_IN + (cb >> 1));
        *(s16x8*)((char*)A + r * 256 + (cb ^ ((r & 7) << 4))) = v;
    }
    __syncthreads();
    int sw = (m & 7) << 4;               // (m+16k)&7 == m&7: same swizzle all four tiles
    f32x4 acc[4][2] = {};
#pragma unroll
    for (int s = 0; s < 4; s++) {
        int co = (s * 64 + q * 16) ^ sw;
        s16x8 a0 = *(const s16x8*)((char*)A + (m     ) * 256 + co);
        s16x8 a1 = *(const s16x8*)((char*)A + (m + 16) * 256 + co);
        s16x8 a2 = *(const s16x8*)((char*)A + (m + 32) * 256 + co);
        s16x8 a3 = *(const s16x8*)((char*)A + (m + 48) * 256 + co);
#pragma unroll
        for (int f = 0; f < 2; f++) {
            acc[0][f] = __builtin_amdgcn_mfma_f32_16x16x32_bf16(a0, bf[s * 2 + f], acc[0][f], 0, 0, 0);
            acc[1][f] = __builtin_amdgcn_mfma_f32_16x16x32_bf16(a1, bf[s * 2 + f], acc[1][f], 0, 0, 0);
            acc[2][f] = __builtin_amdgcn_mfma_f32_16x16x32_bf16(a2, bf[s * 2 + f], acc[2][f], 0, 0, 0);
            acc[3][f] = __builtin_amdgcn_mfma_f32_16x16x32_bf16(a3, bf[s * 2 + f], acc[3][f], 0, 0, 0);
        }
    }
#pragma unroll
    for (int f = 0; f < 2; f++) {
        int col = (w * 2 + f) * 16 + m;
        float s1 = 0.f, s2 = 0.f;
#pragma unroll
        for (int t = 0; t < 4; t++) {
#pragma unroll
            for (int j = 0; j < 4; j++) {
                float v = acc[t][f][j];
                int row = row0 + t * 16 + q * 4 + j;
                if (row < N_NODES) h1B[(size_t)row * D_H + col] = f2bf(v);
                s1 += v; s2 = fmaf(v, v, s2);
            }
        }
        s1 += __shfl_xor(s1, 16, 64); s1 += __shfl_xor(s1, 32, 64);
        s2 += __shfl_xor(s2, 16, 64); s2 += __shfl_xor(s2, 32, 64);
        if (lane < 16) {
            partial[(size_t)blockIdx.x * 512 + col] = s1;
            partial[(size_t)blockIdx.x * 512 + 256 + col] = s2;
        }
    }
}

// ================================================================ BN finalize (NPART block-partials)
__global__ __launch_bounds__(256) void bn_finalize_kernel(const float* __restrict__ partial,
                                                          const float* __restrict__ gamma,
                                                          const float* __restrict__ beta,
                                                          float* __restrict__ scale,
                                                          float* __restrict__ shift) {
    int s = blockIdx.x;
    int tid = threadIdx.x;
    float sum = 0.f, sq = 0.f;
    for (int b = tid; b < NPART; b += 256) {
        sum += partial[(size_t)b * 512 + s];
        sq  += partial[(size_t)b * 512 + 256 + s];
    }
    __shared__ float rs[256], rq[256];
    rs[tid] = sum; rq[tid] = sq;
    __syncthreads();
    for (int off = 128; off > 0; off >>= 1) {
        if (tid < off) { rs[tid] += rs[tid + off]; rq[tid] += rq[tid + off]; }
        __syncthreads();
    }
    if (tid == 0) {
        float inv  = 1.0f / (float)N_NODES;
        float mean = rs[0] * inv;
        float var  = rq[0] * inv - mean * mean;
        float sc   = gamma[s] * rsqrtf(var + 1e-5f);
        scale[s] = sc;
        shift[s] = fmaf(-mean, sc, beta[s]);
    }
}

// ================================================================ GEMM2 (MFMA, MT=64, 8 waves, B-in-registers): h2B = relu(BN1(h1B)) @ W2 + BN2 partials
__global__ __launch_bounds__(512) void gemm2_kernel(const ushort* __restrict__ h1B,
                                                    const ushort* __restrict__ Wp,
                                                    const float* __restrict__ scale1,
                                                    const float* __restrict__ shift1,
                                                    ushort* __restrict__ h2B,
                                                    float* __restrict__ partial) {
    __shared__ ushort A[MT * D_H];    // 64x256 bf16 = 32 KB, row stride 512 B, swizzled
    int tid = threadIdx.x, lane = tid & 63, w = tid >> 6;
    int row0 = blockIdx.x * MT;
    int m = lane & 15, q = lane >> 4;
    const s16x8* B = (const s16x8*)Wp;
    // preload this wave's full B slice: 8 s-steps x 2 col-groups = 16 frags (64 VGPR)
    s16x8 bf[16];
#pragma unroll
    for (int s = 0; s < 8; s++)
#pragma unroll
        for (int f = 0; f < 2; f++)
            bf[s * 2 + f] = B[(s * 16 + w * 2 + f) * 64 + lane];
    // stage A with fused BN1+ReLU
    for (int i = tid; i < 2048; i += 512) {
        int r = i >> 5, cb = (i & 31) << 4;
        int row = row0 + r, c0 = cb >> 1;
        s16x8 o = {};
        if (row < N_NODES) {
            s16x8 in = *(const s16x8*)(h1B + (size_t)row * D_H + c0);
            float4 sc0 = *(const float4*)(scale1 + c0), sc1 = *(const float4*)(scale1 + c0 + 4);
            float4 sh0 = *(const float4*)(shift1 + c0), sh1 = *(const float4*)(shift1 + c0 + 4);
            o[0] = (short)f2bf(fmaxf(fmaf(bf2f((ushort)in[0]), sc0.x, sh0.x), 0.f));
            o[1] = (short)f2bf(fmaxf(fmaf(bf2f((ushort)in[1]), sc0.y, sh0.y), 0.f));
            o[2] = (short)f2bf(fmaxf(fmaf(bf2f((ushort)in[2]), sc0.z, sh0.z), 0.f));
            o[3] = (short)f2bf(fmaxf(fmaf(bf2f((ushort)in[3]), sc0.w, sh0.w), 0.f));
            o[4] = (short)f2bf(fmaxf(fmaf(bf2f((ushort)in[4]), sc1.x, sh1.x), 0.f));
            o[5] = (short)f2bf(fmaxf(fmaf(bf2f((ushort)in[5]), sc1.y, sh1.y), 0.f));
            o[6] = (short)f2bf(fmaxf(fmaf(bf2f((ushort)in[6]), sc1.z, sh1.z), 0.f));
            o[7] = (short)f2bf(fmaxf(fmaf(bf2f((ushort)in[7]), sc1.w, sh1.w), 0.f));
        }
        *(s16x8*)((char*)A + r * 512 + (cb ^ ((r & 7) << 4))) = o;
    }
    __syncthreads();
    int sw = (m & 7) << 4;
    f32x4 acc[4][2] = {};
#pragma unroll
    for (int s = 0; s < 8; s++) {
        int co = (s * 64 + q * 16) ^ sw;
        s16x8 a0 = *(const s16x8*)((char*)A + (m     ) * 512 + co);
        s16x8 a1 = *(const s16x8*)((char*)A + (m + 16) * 512 + co);
        s16x8 a2 = *(const s16x8*)((char*)A + (m + 32) * 512 + co);
        s16x8 a3 = *(const s16x8*)((char*)A + (m + 48) * 512 + co);
#pragma unroll
        for (int f = 0; f < 2; f++) {
            acc[0][f] = __builtin_amdgcn_mfma_f32_16x16x32_bf16(a0, bf[s * 2 + f], acc[0][f], 0, 0, 0);
            acc[1][f] = __builtin_amdgcn_mfma_f32_16x16x32_bf16(a1, bf[s * 2 + f], acc[1][f], 0, 0, 0);
            acc[2][f] = __builtin_amdgcn_mfma_f32_16x16x32_bf16(a2, bf[s * 2 + f], acc[2][f], 0, 0, 0);
            acc[3][f] = __builtin_amdgcn_mfma_f32_16x16x32_bf16(a3, bf[s * 2 + f], acc[3][f], 0, 0, 0);
        }
    }
#pragma unroll
    for (int f = 0; f < 2; f++) {
        int col = (w * 2 + f) * 16 + m;
        float s1 = 0.f, s2 = 0.f;
#pragma unroll
        for (int t = 0; t < 4; t++) {
#pragma unroll
            for (int j = 0; j < 4; j++) {
                float v = acc[t][f][j];
                int row = row0 + t * 16 + q * 4 + j;
                if (row < N_NODES) h2B[(size_t)row * D_H + col] = f2bf(v);
                s1 += v; s2 = fmaf(v, v, s2);
            }
        }
        s1 += __shfl_xor(s1, 16, 64); s1 += __shfl_xor(s1, 32, 64);
        s2 += __shfl_xor(s2, 16, 64); s2 += __shfl_xor(s2, 32, 64);
        if (lane < 16) {
            partial[(size_t)blockIdx.x * 512 + col] = s1;
            partial[(size_t)blockIdx.x * 512 + 256 + col] = s2;
        }
    }
}

// ================================================================ final: out = relu(BN2(h2B)) -> fp32
__global__ __launch_bounds__(256) void bn2_apply_kernel(const ushort* __restrict__ h2B,
                                                        const float* __restrict__ scale,
                                                        const float* __restrict__ shift,
                                                        float* __restrict__ out, int total8) {
    int i = blockIdx.x * 256 + threadIdx.x;
    if (i >= total8) return;
    s16x8 v = ((const s16x8*)h2B)[i];
    int c = (i & 31) << 3;
    float4 sc0 = *(const float4*)(scale + c), sc1 = *(const float4*)(scale + c + 4);
    float4 sh0 = *(const float4*)(shift + c), sh1 = *(const float4*)(shift + c + 4);
    float4 o0, o1;
    o0.x = fmaxf(fmaf(bf2f((ushort)v[0]), sc0.x, sh0.x), 0.f);
    o0.y = fmaxf(fmaf(bf2f((ushort)v[1]), sc0.y, sh0.y), 0.f);
    o0.z = fmaxf(fmaf(bf2f((ushort)v[2]), sc0.z, sh0.z), 0.f);
    o0.w = fmaxf(fmaf(bf2f((ushort)v[3]), sc0.w, sh0.w), 0.f);
    o1.x = fmaxf(fmaf(bf2f((ushort)v[4]), sc1.x, sh1.x), 0.f);
    o1.y = fmaxf(fmaf(bf2f((ushort)v[5]), sc1.y, sh1.y), 0.f);
    o1.z = fmaxf(fmaf(bf2f((ushort)v[6]), sc1.z, sh1.z), 0.f);
    o1.w = fmaxf(fmaf(bf2f((ushort)v[7]), sc1.w, sh1.w), 0.f);
    ((float4*)out)[(size_t)i * 2]     = o0;
    ((float4*)out)[(size_t)i * 2 + 1] = o1;
}

// ================================================================
extern "C" void kernel_launch(void* const* d_in, const int* in_sizes, int n_in,
                              void* d_out, int out_size, void* d_ws, size_t ws_size,
                              hipStream_t stream) {
    const float* x      = (const float*)d_in[0];
    const int*   ei     = (const int*)d_in[1];
    const float* eps    = (const float*)d_in[3];
    const float* W1     = (const float*)d_in[4];
    const float* gamma1 = (const float*)d_in[5];
    const float* beta1  = (const float*)d_in[6];
    const float* W2     = (const float*)d_in[7];
    const float* gamma2 = (const float*)d_in[8];
    const float* beta2  = (const float*)d_in[9];
    int E = in_sizes[1] / 2;

    char* ws = (char*)d_ws;
    ushort* xB     = (ushort*)(ws);                 // 12,800,000 B (dead after gather)
    float*  partial= (float*)(ws);                  // 1,601,536 B  (overlaps xB; live from gemm1)
    ushort* hB     = (ushort*)(ws + 12800000);      // 12,800,000 B
    ushort* h1B    = (ushort*)(ws + 25600000);      // 25,600,000 B
    ushort* h2B    = (ushort*)(ws + 51200000);      // 25,600,000 B (overlaps bucket scratch)
    float*  stats  = (float*)(ws + 76800000);       // 4,096 B
    ushort* Wp1    = (ushort*)(ws + 76804096);      // 65,536 B
    ushort* Wp2    = (ushort*)(ws + 76869632);      // 131,072 B -> end 77,000,704
    float* scale1 = stats, *shift1 = stats + 256, *scale2 = stats + 512, *shift2 = stats + 768;
    float* out = (float*)d_out;

    int*  bucket_fill = (int*)(ws + 51200000);      // 391*4 -> pad 2048
    uint* bucket_buf  = (uint*)(ws + 51202048);     // 391*3072*4 = 4,804,608 B

    prep_kernel<<<3174, 256, 0, stream>>>(x, W1, W2, xB, Wp1, Wp2, bucket_fill);
    bucket_kernel<<<(E + EPB - 1) / EPB, 256, 0, stream>>>(ei, bucket_fill, bucket_buf, E);
    gather_bucket_kernel<<<NBKT, 512, 0, stream>>>(xB, eps, bucket_fill, bucket_buf, hB);

    gemm1_kernel<<<NGB, 512, 0, stream>>>(hB, Wp1, h1B, partial);
    bn_finalize_kernel<<<D_H, 256, 0, stream>>>(partial, gamma1, beta1, scale1, shift1);
    gemm2_kernel<<<NGB, 512, 0, stream>>>(h1B, Wp2, scale1, shift1, h2B, partial);
    bn_finalize_kernel<<<D_H, 256, 0, stream>>>(partial, gamma2, beta2, scale2, shift2);
    bn2_apply_kernel<<<(1600000 + 255) / 256, 256, 0, stream>>>(h2B, scale2, shift2, out, 1600000);
}